// Round 1
// baseline (2714.280 us; speedup 1.0000x reference)
//
#include <hip/hip_runtime.h>
#include <stdint.h>

// Problem constants
#define B_SZ 32
#define SEQ  512
#define DIM  768
#define NH   12
#define HD   64
#define ROWS (B_SZ*SEQ)   // 16384

typedef __attribute__((ext_vector_type(4))) float f32x4;
typedef __attribute__((ext_vector_type(8))) short short8;

__device__ __forceinline__ unsigned short f2bf(float f){
  uint32_t x = __float_as_uint(f);
  uint32_t r = (x + 0x7fffu + ((x >> 16) & 1u)) >> 16;   // RNE
  return (unsigned short)r;
}
__device__ __forceinline__ float bf2f(unsigned short u){
  return __uint_as_float(((uint32_t)u) << 16);
}

// ---------------- prep kernels ----------------
// split x (fp32 -> hi/lo bf16), 4 elems/thread
__global__ void k_split4(const float* __restrict__ x,
                         unsigned short* __restrict__ xh,
                         unsigned short* __restrict__ xl, int n4){
  int i = blockIdx.x * 256 + threadIdx.x;
  if (i >= n4) return;
  float4 v = ((const float4*)x)[i];
  ushort4 h, l;
  h.x = f2bf(v.x); l.x = f2bf(v.x - bf2f(h.x));
  h.y = f2bf(v.y); l.y = f2bf(v.y - bf2f(h.y));
  h.z = f2bf(v.z); l.z = f2bf(v.z - bf2f(h.z));
  h.w = f2bf(v.w); l.w = f2bf(v.w - bf2f(h.w));
  ((ushort4*)xh)[i] = h;
  ((ushort4*)xl)[i] = l;
}

// QT[h][e][d] = split(Q[h][d][e])  (transpose for NT GEMM)
__global__ void k_transQ(const float* __restrict__ Q,
                         unsigned short* __restrict__ qth,
                         unsigned short* __restrict__ qtl){
  int i = blockIdx.x * 256 + threadIdx.x;      // over 12*768*768, exact grid
  int e = i % DIM; int t2 = i / DIM; int d = t2 % DIM; int h = t2 / DIM;
  float v = Q[i];
  size_t o = ((size_t)h * DIM + e) * DIM + d;
  unsigned short hi = f2bf(v);
  qth[o] = hi;
  qtl[o] = f2bf(v - bf2f(hi));
}

// Vt[h][e][d] = bf16(V[h][d][e])
__global__ void k_transV(const float* __restrict__ V,
                         unsigned short* __restrict__ vt){
  int i = blockIdx.x * 256 + threadIdx.x;      // over 12*768*64, exact grid
  int e = i % HD; int t2 = i / HD; int d = t2 % DIM; int h = t2 / DIM;
  size_t o = ((size_t)h * HD + e) * DIM + d;
  vt[o] = f2bf(V[i]);
}

// ---------------- xV GEMM (plain bf16) ----------------
// xvT[(b*NH+h)*64 + e][n] = sum_d x[b,n,d] * V[h,d,e]
// grid: (4 ntiles, 32 b, 12 h), block 256. tile: 128 n-rows x 64 e-cols, BK=32.
__global__ __launch_bounds__(256) void k_gemm_xv(
    const unsigned short* __restrict__ xh,
    const unsigned short* __restrict__ vt,
    unsigned short* __restrict__ xvT){
  __shared__ __align__(16) unsigned short lA[128*32];
  __shared__ __align__(16) unsigned short lB[64*32];
  int t = threadIdx.x, w = t >> 6, l = t & 63;
  int lane16 = l & 15, quad = l >> 4;
  int b = blockIdx.y, h = blockIdx.z;
  int m0 = blockIdx.x * 128;
  const unsigned short* vth = vt + (size_t)h * HD * DIM;
  f32x4 acc[2][4];
  for (int i = 0; i < 2; ++i) for (int j = 0; j < 4; ++j)
    for (int z = 0; z < 4; ++z) acc[i][j][z] = 0.f;

  for (int kt = 0; kt < DIM/32; ++kt){
    int k0 = kt * 32;
    __syncthreads();
    for (int rep = 0; rep < 2; ++rep){
      int id = t + rep * 256;              // 0..511
      int row = id >> 2, ko = (id & 3) * 8;
      *(int4*)&lA[row*32 + ko] =
        *(const int4*)&xh[((size_t)(b*SEQ + m0 + row))*DIM + k0 + ko];
    }
    { int row = t >> 2, ko = (t & 3) * 8;  // 64x32
      *(int4*)&lB[row*32 + ko] = *(const int4*)&vth[(size_t)row*DIM + k0 + ko]; }
    __syncthreads();
    short8 a[2];
    for (int i = 0; i < 2; ++i)
      a[i] = *(const short8*)&lA[(w*32 + i*16 + lane16)*32 + quad*8];
    for (int j = 0; j < 4; ++j){
      short8 bb = *(const short8*)&lB[(j*16 + lane16)*32 + quad*8];
      for (int i = 0; i < 2; ++i)
        acc[i][j] = __builtin_amdgcn_mfma_f32_16x16x32_bf16(a[i], bb, acc[i][j], 0, 0, 0);
    }
  }
  for (int i = 0; i < 2; ++i) for (int j = 0; j < 4; ++j) for (int r = 0; r < 4; ++r){
    int col = j*16 + lane16;
    int n = m0 + w*32 + i*16 + quad*4 + r;
    xvT[((size_t)(b*NH + h)*HD + col)*SEQ + n] = f2bf(acc[i][j][r]);
  }
}

// ---------------- q projection (split 3-pass) ----------------
// q[bn][e] = sum_d x[bn][d] * Q_h[d][e]; A = x (hi/lo), Bt = QT_h (hi/lo)
// grid (128 Mtiles, 6 Ntiles), block 256. tile 128x128, BK=32.
__global__ __launch_bounds__(256) void k_gemm_q(
    const unsigned short* __restrict__ xh, const unsigned short* __restrict__ xl,
    const unsigned short* __restrict__ bth, const unsigned short* __restrict__ btl,
    unsigned short* __restrict__ qh, unsigned short* __restrict__ ql){
  __shared__ __align__(16) unsigned short lA[2][128*32];
  __shared__ __align__(16) unsigned short lB[2][128*32];
  int t = threadIdx.x, w = t >> 6, l = t & 63;
  int lane16 = l & 15, quad = l >> 4;
  int m0 = blockIdx.x * 128, n0 = blockIdx.y * 128;
  int wr = (w >> 1) * 64, wc = (w & 1) * 64;
  f32x4 acc[4][4];
  for (int i = 0; i < 4; ++i) for (int j = 0; j < 4; ++j)
    for (int z = 0; z < 4; ++z) acc[i][j][z] = 0.f;

  for (int kt = 0; kt < DIM/32; ++kt){
    int k0 = kt * 32;
    __syncthreads();
    for (int rep = 0; rep < 2; ++rep){
      int id = t + rep * 256;
      int row = id >> 2, ko = (id & 3) * 8;
      *(int4*)&lA[0][row*32 + ko] = *(const int4*)&xh[(size_t)(m0+row)*DIM + k0 + ko];
      *(int4*)&lA[1][row*32 + ko] = *(const int4*)&xl[(size_t)(m0+row)*DIM + k0 + ko];
      *(int4*)&lB[0][row*32 + ko] = *(const int4*)&bth[(size_t)(n0+row)*DIM + k0 + ko];
      *(int4*)&lB[1][row*32 + ko] = *(const int4*)&btl[(size_t)(n0+row)*DIM + k0 + ko];
    }
    __syncthreads();
    short8 aH[4], aL[4];
    for (int i = 0; i < 4; ++i){
      int r = wr + i*16 + lane16;
      aH[i] = *(const short8*)&lA[0][r*32 + quad*8];
      aL[i] = *(const short8*)&lA[1][r*32 + quad*8];
    }
    for (int j = 0; j < 4; ++j){
      int c = wc + j*16 + lane16;
      short8 bH = *(const short8*)&lB[0][c*32 + quad*8];
      short8 bL = *(const short8*)&lB[1][c*32 + quad*8];
      for (int i = 0; i < 4; ++i){
        acc[i][j] = __builtin_amdgcn_mfma_f32_16x16x32_bf16(aL[i], bH, acc[i][j], 0, 0, 0);
        acc[i][j] = __builtin_amdgcn_mfma_f32_16x16x32_bf16(aH[i], bL, acc[i][j], 0, 0, 0);
        acc[i][j] = __builtin_amdgcn_mfma_f32_16x16x32_bf16(aH[i], bH, acc[i][j], 0, 0, 0);
      }
    }
  }
  for (int i = 0; i < 4; ++i) for (int j = 0; j < 4; ++j) for (int r = 0; r < 4; ++r){
    int row = m0 + wr + i*16 + quad*4 + r;
    int col = n0 + wc + j*16 + lane16;
    float v = acc[i][j][r];
    unsigned short hh = f2bf(v);
    size_t o = (size_t)row*DIM + col;
    qh[o] = hh;
    ql[o] = f2bf(v - bf2f(hh));
  }
}

// ---------------- fused attention per head ----------------
// grid (8 ntiles, 32 b), block 256 (4 waves). BM=64 q-rows, full 512 keys.
// Phase1: S = q @ x^T (split 3-pass), wave w owns keys [128w,128w+128), S in regs.
// Phase2: stable softmax (shfl + LDS stats), P -> LDS (bf16, unnormalized).
// Phase3: O = P @ xvT^T, waves split K, cross-wave reduce in LDS, normalize, store.
__global__ __launch_bounds__(256) void k_attn(
    const unsigned short* __restrict__ qh, const unsigned short* __restrict__ ql,
    const unsigned short* __restrict__ xh, const unsigned short* __restrict__ xl,
    const unsigned short* __restrict__ xvT,
    float* __restrict__ out, int h){
  __shared__ __align__(16) unsigned short lKeys[2][SEQ*32];   // 64 KB (later: xvT 64x512)
  __shared__ __align__(16) unsigned short lQ[2][64*32];       // 8 KB
  __shared__ __align__(16) unsigned short lP[64*SEQ];         // 64 KB (later: fp32 partials)
  __shared__ float lStat[4*64 + 64 + 64];                     // 1.5 KB

  int t = threadIdx.x, w = t >> 6, l = t & 63;
  int lane16 = l & 15, quad = l >> 4;
  int nt = blockIdx.x, b = blockIdx.y;
  int n0 = nt * 64;
  size_t rowbase = (size_t)b * SEQ;

  f32x4 accS[4][8];
  for (int i = 0; i < 4; ++i) for (int j = 0; j < 8; ++j)
    for (int z = 0; z < 4; ++z) accS[i][j][z] = 0.f;

  // ---- Phase 1: scores ----
  for (int kt = 0; kt < DIM/32; ++kt){
    int k0 = kt * 32;
    __syncthreads();
    { int row = t >> 2, ko = (t & 3) * 8;   // q tile 64x32 hi+lo
      *(int4*)&lQ[0][row*32 + ko] = *(const int4*)&qh[(rowbase + n0 + row)*DIM + k0 + ko];
      *(int4*)&lQ[1][row*32 + ko] = *(const int4*)&ql[(rowbase + n0 + row)*DIM + k0 + ko]; }
    for (int rep = 0; rep < 8; ++rep){      // keys 512x32 hi+lo
      int id = t + rep * 256;
      int row = id >> 2, ko = (id & 3) * 8;
      *(int4*)&lKeys[0][row*32 + ko] = *(const int4*)&xh[(rowbase + row)*DIM + k0 + ko];
      *(int4*)&lKeys[1][row*32 + ko] = *(const int4*)&xl[(rowbase + row)*DIM + k0 + ko];
    }
    __syncthreads();
    short8 aH[4], aL[4];
    for (int i = 0; i < 4; ++i){
      int r = i*16 + lane16;
      aH[i] = *(const short8*)&lQ[0][r*32 + quad*8];
      aL[i] = *(const short8*)&lQ[1][r*32 + quad*8];
    }
    for (int j = 0; j < 8; ++j){
      int c = w*128 + j*16 + lane16;
      short8 bH = *(const short8*)&lKeys[0][c*32 + quad*8];
      short8 bL = *(const short8*)&lKeys[1][c*32 + quad*8];
      for (int i = 0; i < 4; ++i){
        accS[i][j] = __builtin_amdgcn_mfma_f32_16x16x32_bf16(aL[i], bH, accS[i][j], 0, 0, 0);
        accS[i][j] = __builtin_amdgcn_mfma_f32_16x16x32_bf16(aH[i], bL, accS[i][j], 0, 0, 0);
        accS[i][j] = __builtin_amdgcn_mfma_f32_16x16x32_bf16(aH[i], bH, accS[i][j], 0, 0, 0);
      }
    }
  }
  __syncthreads();   // all reads of lKeys done

  // stage xvT[b,h] (64 e x 512 n) into lKeys area
  unsigned short* lXv = &lKeys[0][0];
  for (int rep = 0; rep < 16; ++rep){
    int id = t + rep * 256;                // 0..4095
    int e = id >> 6, no = (id & 63) * 8;
    *(int4*)&lXv[e*SEQ + no] =
      *(const int4*)&xvT[((size_t)(b*NH + h)*HD + e)*SEQ + no];
  }

  // ---- Phase 2: softmax ----
  float rmx[4][4];
  for (int i = 0; i < 4; ++i) for (int r = 0; r < 4; ++r){
    float m = accS[i][0][r];
    for (int j = 1; j < 8; ++j) m = fmaxf(m, accS[i][j][r]);
    for (int d = 1; d < 16; d <<= 1) m = fmaxf(m, __shfl_xor(m, d, 64));
    rmx[i][r] = m;
  }
  if (lane16 == 0)
    for (int i = 0; i < 4; ++i) for (int r = 0; r < 4; ++r)
      lStat[w*64 + i*16 + quad*4 + r] = rmx[i][r];
  __syncthreads();
  if (t < 64){
    float m = lStat[t];
    for (int ww = 1; ww < 4; ++ww) m = fmaxf(m, lStat[ww*64 + t]);
    lStat[256 + t] = m;
  }
  __syncthreads();
  float rsum[4][4];
  for (int i = 0; i < 4; ++i) for (int r = 0; r < 4; ++r){
    float g = lStat[256 + i*16 + quad*4 + r];
    float s = 0.f;
    for (int j = 0; j < 8; ++j){
      float p = __expf(accS[i][j][r] - g);
      s += p;
      lP[(i*16 + quad*4 + r)*SEQ + (w*128 + j*16 + lane16)] = f2bf(p);
    }
    for (int d = 1; d < 16; d <<= 1) s += __shfl_xor(s, d, 64);
    rsum[i][r] = s;
  }
  if (lane16 == 0)
    for (int i = 0; i < 4; ++i) for (int r = 0; r < 4; ++r)
      lStat[w*64 + i*16 + quad*4 + r] = rsum[i][r];
  __syncthreads();
  if (t < 64){
    float s = lStat[t];
    for (int ww = 1; ww < 4; ++ww) s += lStat[ww*64 + t];
    lStat[320 + t] = s;
  }
  __syncthreads();   // P + xv + sums all visible

  // ---- Phase 3: PV ----
  f32x4 accO[4][4];
  for (int i = 0; i < 4; ++i) for (int j = 0; j < 4; ++j)
    for (int z = 0; z < 4; ++z) accO[i][j][z] = 0.f;
  for (int ks = 0; ks < 4; ++ks){
    int kb = w*128 + ks*32;
    short8 aP[4];
    for (int i = 0; i < 4; ++i)
      aP[i] = *(const short8*)&lP[(i*16 + lane16)*SEQ + kb + quad*8];
    for (int j = 0; j < 4; ++j){
      short8 bV = *(const short8*)&lXv[(j*16 + lane16)*SEQ + kb + quad*8];
      for (int i = 0; i < 4; ++i)
        accO[i][j] = __builtin_amdgcn_mfma_f32_16x16x32_bf16(aP[i], bV, accO[i][j], 0, 0, 0);
    }
  }
  __syncthreads();   // all reads of lP done before overwrite
  float* red = (float*)lP;
  for (int i = 0; i < 4; ++i) for (int j = 0; j < 4; ++j) for (int r = 0; r < 4; ++r)
    red[w*4096 + (i*16 + quad*4 + r)*64 + (j*16 + lane16)] = accO[i][j][r];
  __syncthreads();
  for (int z = t; z < 4096; z += 256){
    int row = z >> 6, col = z & 63;
    float v = red[z] + red[4096 + z] + red[8192 + z] + red[12288 + z];
    v /= lStat[320 + row];
    out[(rowbase + n0 + row)*DIM + h*HD + col] = v;
  }
}

// ---------------- launcher ----------------
extern "C" void kernel_launch(void* const* d_in, const int* in_sizes, int n_in,
                              void* d_out, int out_size, void* d_ws, size_t ws_size,
                              hipStream_t stream){
  const float* x = (const float*)d_in[0];
  const float* Q = (const float*)d_in[1];
  const float* V = (const float*)d_in[2];
  float* out = (float*)d_out;

  char* ws = (char*)d_ws;
  size_t off = 0;
  auto alloc = [&](size_t bytes) -> void* {
    void* p = ws + off;
    off += (bytes + 255) & ~(size_t)255;
    return p;
  };
  unsigned short* xh  = (unsigned short*)alloc((size_t)ROWS*DIM*2);       // 25.2 MB
  unsigned short* xl  = (unsigned short*)alloc((size_t)ROWS*DIM*2);       // 25.2 MB
  unsigned short* qth = (unsigned short*)alloc((size_t)NH*DIM*DIM*2);     // 14.2 MB
  unsigned short* qtl = (unsigned short*)alloc((size_t)NH*DIM*DIM*2);     // 14.2 MB
  unsigned short* vt  = (unsigned short*)alloc((size_t)NH*HD*DIM*2);      //  1.2 MB
  unsigned short* xvT = (unsigned short*)alloc((size_t)B_SZ*NH*HD*SEQ*2); // 25.2 MB
  unsigned short* qh  = (unsigned short*)alloc((size_t)ROWS*DIM*2);       // 25.2 MB
  unsigned short* ql  = (unsigned short*)alloc((size_t)ROWS*DIM*2);       // 25.2 MB
  // total ~155.6 MB

  int n4 = ROWS*DIM/4;                                  // 3,145,728
  k_split4<<<n4/256, 256, 0, stream>>>(x, xh, xl, n4);
  k_transQ<<<NH*DIM*DIM/256, 256, 0, stream>>>(Q, qth, qtl);
  k_transV<<<NH*DIM*HD/256, 256, 0, stream>>>(V, vt);
  k_gemm_xv<<<dim3(4, B_SZ, NH), 256, 0, stream>>>(xh, vt, xvT);

  for (int h = 0; h < NH; ++h){
    k_gemm_q<<<dim3(ROWS/128, DIM/128), 256, 0, stream>>>(
        xh, xl, qth + (size_t)h*DIM*DIM, qtl + (size_t)h*DIM*DIM, qh, ql);
    k_attn<<<dim3(SEQ/64, B_SZ), 256, 0, stream>>>(qh, ql, xh, xl, xvT, out, h);
  }
}

// Round 2
// 2610.656 us; speedup vs baseline: 1.0397x; 1.0397x over previous
//
#include <hip/hip_runtime.h>
#include <stdint.h>

// Problem constants
#define B_SZ 32
#define SEQ  512
#define DIM  768
#define NH   12
#define HD   64
#define ROWS (B_SZ*SEQ)   // 16384

typedef __attribute__((ext_vector_type(4))) float f32x4;
typedef __attribute__((ext_vector_type(8))) short short8;

// async global->LDS, 16B per lane; LDS dest = wave-uniform base + lane*16
#define GLOAD_LDS16(gaddr, laddr) \
  __builtin_amdgcn_global_load_lds((const __attribute__((address_space(1))) void*)(gaddr), \
                                   (__attribute__((address_space(3))) void*)(laddr), 16, 0, 0)

__device__ __forceinline__ unsigned short f2bf(float f){
  uint32_t x = __float_as_uint(f);
  uint32_t r = (x + 0x7fffu + ((x >> 16) & 1u)) >> 16;   // RNE
  return (unsigned short)r;
}
__device__ __forceinline__ float bf2f(unsigned short u){
  return __uint_as_float(((uint32_t)u) << 16);
}

// ---------------- prep kernels ----------------
// split x (fp32 -> hi/lo bf16), 4 elems/thread
__global__ void k_split4(const float* __restrict__ x,
                         unsigned short* __restrict__ xh,
                         unsigned short* __restrict__ xl, int n4){
  int i = blockIdx.x * 256 + threadIdx.x;
  if (i >= n4) return;
  float4 v = ((const float4*)x)[i];
  ushort4 h, l;
  h.x = f2bf(v.x); l.x = f2bf(v.x - bf2f(h.x));
  h.y = f2bf(v.y); l.y = f2bf(v.y - bf2f(h.y));
  h.z = f2bf(v.z); l.z = f2bf(v.z - bf2f(h.z));
  h.w = f2bf(v.w); l.w = f2bf(v.w - bf2f(h.w));
  ((ushort4*)xh)[i] = h;
  ((ushort4*)xl)[i] = l;
}

// QT[h][e][d] = split(Q[h][d][e]) — LDS-tiled transpose, both sides coalesced
__global__ __launch_bounds__(256) void k_transQ(const float* __restrict__ Q,
                         unsigned short* __restrict__ qth,
                         unsigned short* __restrict__ qtl){
  __shared__ float tile[32][33];
  int h = blockIdx.z;
  int d0 = blockIdx.x * 32;   // input row tile
  int e0 = blockIdx.y * 32;   // input col tile
  int tx = threadIdx.x & 31, ty = threadIdx.x >> 5;  // 32 x 8
  const float* Qh = Q + (size_t)h * DIM * DIM;
  for (int i = 0; i < 4; ++i)
    tile[ty + i*8][tx] = Qh[(size_t)(d0 + ty + i*8) * DIM + e0 + tx];
  __syncthreads();
  for (int i = 0; i < 4; ++i){
    float v = tile[tx][ty + i*8];
    size_t o = ((size_t)h * DIM + e0 + ty + i*8) * DIM + d0 + tx;
    unsigned short hi = f2bf(v);
    qth[o] = hi;
    qtl[o] = f2bf(v - bf2f(hi));
  }
}

// Vt[h][e][d] = bf16(V[h][d][e]) — LDS-tiled transpose
__global__ __launch_bounds__(256) void k_transV(const float* __restrict__ V,
                         unsigned short* __restrict__ vt){
  __shared__ float tile[32][33];
  int h = blockIdx.z;
  int d0 = blockIdx.x * 32;   // input row tile (d)
  int e0 = blockIdx.y * 32;   // input col tile (e)
  int tx = threadIdx.x & 31, ty = threadIdx.x >> 5;
  const float* Vh = V + (size_t)h * DIM * HD;
  for (int i = 0; i < 4; ++i)
    tile[ty + i*8][tx] = Vh[(size_t)(d0 + ty + i*8) * HD + e0 + tx];
  __syncthreads();
  for (int i = 0; i < 4; ++i)
    vt[((size_t)h * HD + e0 + ty + i*8) * DIM + d0 + tx] = f2bf(tile[tx][ty + i*8]);
}

// ---------------- xV GEMM (plain bf16) ----------------
// xvT[(b*NH+h)*64 + e][n] = sum_d x[b,n,d] * V[h,d,e]
// grid: (4 ntiles, 32 b, 12 h), block 256. tile: 128 n-rows x 64 e-cols, BK=32.
__global__ __launch_bounds__(256) void k_gemm_xv(
    const unsigned short* __restrict__ xh,
    const unsigned short* __restrict__ vt,
    unsigned short* __restrict__ xvT){
  __shared__ __align__(16) unsigned short lA[128*32];
  __shared__ __align__(16) unsigned short lB[64*32];
  __shared__ __align__(16) unsigned short lOut[64*128];
  int t = threadIdx.x, w = t >> 6, l = t & 63;
  int lane16 = l & 15, quad = l >> 4;
  int b = blockIdx.y, h = blockIdx.z;
  int m0 = blockIdx.x * 128;
  const unsigned short* vth = vt + (size_t)h * HD * DIM;
  f32x4 acc[2][4];
  for (int i = 0; i < 2; ++i) for (int j = 0; j < 4; ++j)
    for (int z = 0; z < 4; ++z) acc[i][j][z] = 0.f;

  for (int kt = 0; kt < DIM/32; ++kt){
    int k0 = kt * 32;
    __syncthreads();
    for (int rep = 0; rep < 2; ++rep){
      int id = t + rep * 256;              // 0..511
      int row = id >> 2, ko = (id & 3) * 8;
      GLOAD_LDS16(&xh[((size_t)(b*SEQ + m0 + row))*DIM + k0 + ko],
                  &lA[(rep*256 + w*64) * 8]);
    }
    { int row = t >> 2, ko = (t & 3) * 8;  // 64x32
      GLOAD_LDS16(&vth[(size_t)row*DIM + k0 + ko], &lB[(w*64) * 8]); }
    __syncthreads();
    short8 a[2];
    for (int i = 0; i < 2; ++i)
      a[i] = *(const short8*)&lA[(w*32 + i*16 + lane16)*32 + quad*8];
    for (int j = 0; j < 4; ++j){
      short8 bb = *(const short8*)&lB[(j*16 + lane16)*32 + quad*8];
      for (int i = 0; i < 2; ++i)
        acc[i][j] = __builtin_amdgcn_mfma_f32_16x16x32_bf16(a[i], bb, acc[i][j], 0, 0, 0);
    }
  }
  // epilogue: transpose through LDS, contiguous 256B row stores
  __syncthreads();
  for (int i = 0; i < 2; ++i) for (int j = 0; j < 4; ++j) for (int r = 0; r < 4; ++r){
    int col = j*16 + lane16;                      // e (0..63)
    int n  = w*32 + i*16 + quad*4 + r;            // local n (0..127)
    lOut[col*128 + n] = f2bf(acc[i][j][r]);
  }
  __syncthreads();
  for (int rep = 0; rep < 4; ++rep){
    int id = t + rep*256;                         // 0..1023 int4s
    int e = id >> 4, no = (id & 15) * 8;
    *(int4*)&xvT[((size_t)(b*NH + h)*HD + e)*SEQ + m0 + no] = *(const int4*)&lOut[e*128 + no];
  }
}

// ---------------- q projection (split 3-pass) ----------------
// q[bn][e] = sum_d x[bn][d] * Q_h[d][e]; A = x (hi/lo), Bt = QT_h (hi/lo)
// grid (128 Mtiles, 6 Ntiles), block 256. tile 128x128, BK=32.
__global__ __launch_bounds__(256) void k_gemm_q(
    const unsigned short* __restrict__ xh, const unsigned short* __restrict__ xl,
    const unsigned short* __restrict__ bth, const unsigned short* __restrict__ btl,
    unsigned short* __restrict__ qh, unsigned short* __restrict__ ql){
  __shared__ __align__(16) unsigned short lA[2][128*32];
  __shared__ __align__(16) unsigned short lB[2][128*32];
  int t = threadIdx.x, w = t >> 6, l = t & 63;
  int lane16 = l & 15, quad = l >> 4;
  int m0 = blockIdx.x * 128, n0 = blockIdx.y * 128;
  int wr = (w >> 1) * 64, wc = (w & 1) * 64;
  f32x4 acc[4][4];
  for (int i = 0; i < 4; ++i) for (int j = 0; j < 4; ++j)
    for (int z = 0; z < 4; ++z) acc[i][j][z] = 0.f;

  for (int kt = 0; kt < DIM/32; ++kt){
    int k0 = kt * 32;
    __syncthreads();
    for (int rep = 0; rep < 2; ++rep){
      int id = t + rep * 256;
      int row = id >> 2, ko = (id & 3) * 8;
      int lb = (rep*256 + w*64) * 8;
      GLOAD_LDS16(&xh [(size_t)(m0+row)*DIM + k0 + ko], &lA[0][lb]);
      GLOAD_LDS16(&xl [(size_t)(m0+row)*DIM + k0 + ko], &lA[1][lb]);
      GLOAD_LDS16(&bth[(size_t)(n0+row)*DIM + k0 + ko], &lB[0][lb]);
      GLOAD_LDS16(&btl[(size_t)(n0+row)*DIM + k0 + ko], &lB[1][lb]);
    }
    __syncthreads();
    short8 aH[4], aL[4];
    for (int i = 0; i < 4; ++i){
      int r = wr + i*16 + lane16;
      aH[i] = *(const short8*)&lA[0][r*32 + quad*8];
      aL[i] = *(const short8*)&lA[1][r*32 + quad*8];
    }
    for (int j = 0; j < 4; ++j){
      int c = wc + j*16 + lane16;
      short8 bH = *(const short8*)&lB[0][c*32 + quad*8];
      short8 bL = *(const short8*)&lB[1][c*32 + quad*8];
      for (int i = 0; i < 4; ++i){
        acc[i][j] = __builtin_amdgcn_mfma_f32_16x16x32_bf16(aL[i], bH, acc[i][j], 0, 0, 0);
        acc[i][j] = __builtin_amdgcn_mfma_f32_16x16x32_bf16(aH[i], bL, acc[i][j], 0, 0, 0);
        acc[i][j] = __builtin_amdgcn_mfma_f32_16x16x32_bf16(aH[i], bH, acc[i][j], 0, 0, 0);
      }
    }
  }
  for (int i = 0; i < 4; ++i) for (int j = 0; j < 4; ++j) for (int r = 0; r < 4; ++r){
    int row = m0 + wr + i*16 + quad*4 + r;
    int col = n0 + wc + j*16 + lane16;
    float v = acc[i][j][r];
    unsigned short hh = f2bf(v);
    size_t o = (size_t)row*DIM + col;
    qh[o] = hh;
    ql[o] = f2bf(v - bf2f(hh));
  }
}

// ---------------- fused attention per head ----------------
// grid (8 ntiles, 32 b), block 256 (4 waves). BM=64 q-rows, full 512 keys.
// Phase1: S = q @ x^T (split 3-pass), wave w owns keys [128w,128w+128), S in regs.
// Phase2: stable softmax (shfl + LDS stats), P -> LDS (bf16, unnormalized).
// Phase3: O = P @ xvT^T, waves split K, cross-wave reduce in LDS, normalize, store.
__global__ __launch_bounds__(256) void k_attn(
    const unsigned short* __restrict__ qh, const unsigned short* __restrict__ ql,
    const unsigned short* __restrict__ xh, const unsigned short* __restrict__ xl,
    const unsigned short* __restrict__ xvT,
    float* __restrict__ out, int h){
  __shared__ __align__(16) unsigned short lKeys[2][SEQ*32];   // 64 KB (later: xvT 64x512)
  __shared__ __align__(16) unsigned short lQ[2][64*32];       // 8 KB
  __shared__ __align__(16) unsigned short lP[64*SEQ];         // 64 KB (later: fp32 partials)
  __shared__ float lStat[4*64 + 64 + 64];                     // 1.5 KB

  int t = threadIdx.x, w = t >> 6, l = t & 63;
  int lane16 = l & 15, quad = l >> 4;
  int nt = blockIdx.x, b = blockIdx.y;
  int n0 = nt * 64;
  size_t rowbase = (size_t)b * SEQ;

  f32x4 accS[4][8];
  for (int i = 0; i < 4; ++i) for (int j = 0; j < 8; ++j)
    for (int z = 0; z < 4; ++z) accS[i][j][z] = 0.f;

  // ---- Phase 1: scores ----
  for (int kt = 0; kt < DIM/32; ++kt){
    int k0 = kt * 32;
    __syncthreads();
    { int row = t >> 2, ko = (t & 3) * 8;   // q tile 64x32 hi+lo
      int lb = (w*64) * 8;
      GLOAD_LDS16(&qh[(rowbase + n0 + row)*DIM + k0 + ko], &lQ[0][lb]);
      GLOAD_LDS16(&ql[(rowbase + n0 + row)*DIM + k0 + ko], &lQ[1][lb]); }
    for (int rep = 0; rep < 8; ++rep){      // keys 512x32 hi+lo
      int id = t + rep * 256;
      int row = id >> 2, ko = (id & 3) * 8;
      int lb = (rep*256 + w*64) * 8;
      GLOAD_LDS16(&xh[(rowbase + row)*DIM + k0 + ko], &lKeys[0][lb]);
      GLOAD_LDS16(&xl[(rowbase + row)*DIM + k0 + ko], &lKeys[1][lb]);
    }
    __syncthreads();
    short8 aH[4], aL[4];
    for (int i = 0; i < 4; ++i){
      int r = i*16 + lane16;
      aH[i] = *(const short8*)&lQ[0][r*32 + quad*8];
      aL[i] = *(const short8*)&lQ[1][r*32 + quad*8];
    }
    for (int j = 0; j < 8; ++j){
      int c = w*128 + j*16 + lane16;
      short8 bH = *(const short8*)&lKeys[0][c*32 + quad*8];
      short8 bL = *(const short8*)&lKeys[1][c*32 + quad*8];
      for (int i = 0; i < 4; ++i){
        accS[i][j] = __builtin_amdgcn_mfma_f32_16x16x32_bf16(aL[i], bH, accS[i][j], 0, 0, 0);
        accS[i][j] = __builtin_amdgcn_mfma_f32_16x16x32_bf16(aH[i], bL, accS[i][j], 0, 0, 0);
        accS[i][j] = __builtin_amdgcn_mfma_f32_16x16x32_bf16(aH[i], bH, accS[i][j], 0, 0, 0);
      }
    }
  }
  __syncthreads();   // all reads of lKeys done

  // stage xvT[b,h] (64 e x 512 n) into lKeys area (async; drained by next barrier)
  unsigned short* lXv = &lKeys[0][0];
  for (int rep = 0; rep < 16; ++rep){
    int id = t + rep * 256;                // 0..4095 int4s
    int e = id >> 6, no = (id & 63) * 8;
    GLOAD_LDS16(&xvT[((size_t)(b*NH + h)*HD + e)*SEQ + no],
                &lXv[(rep*256 + w*64) * 8]);
  }

  // ---- Phase 2: softmax ----
  float rmx[4][4];
  for (int i = 0; i < 4; ++i) for (int r = 0; r < 4; ++r){
    float m = accS[i][0][r];
    for (int j = 1; j < 8; ++j) m = fmaxf(m, accS[i][j][r]);
    for (int d = 1; d < 16; d <<= 1) m = fmaxf(m, __shfl_xor(m, d, 64));
    rmx[i][r] = m;
  }
  if (lane16 == 0)
    for (int i = 0; i < 4; ++i) for (int r = 0; r < 4; ++r)
      lStat[w*64 + i*16 + quad*4 + r] = rmx[i][r];
  __syncthreads();
  if (t < 64){
    float m = lStat[t];
    for (int ww = 1; ww < 4; ++ww) m = fmaxf(m, lStat[ww*64 + t]);
    lStat[256 + t] = m;
  }
  __syncthreads();
  float rsum[4][4];
  for (int i = 0; i < 4; ++i) for (int r = 0; r < 4; ++r){
    float g = lStat[256 + i*16 + quad*4 + r];
    float s = 0.f;
    for (int j = 0; j < 8; ++j){
      float p = __expf(accS[i][j][r] - g);
      s += p;
      lP[(i*16 + quad*4 + r)*SEQ + (w*128 + j*16 + lane16)] = f2bf(p);
    }
    for (int d = 1; d < 16; d <<= 1) s += __shfl_xor(s, d, 64);
    rsum[i][r] = s;
  }
  if (lane16 == 0)
    for (int i = 0; i < 4; ++i) for (int r = 0; r < 4; ++r)
      lStat[w*64 + i*16 + quad*4 + r] = rsum[i][r];
  __syncthreads();
  if (t < 64){
    float s = lStat[t];
    for (int ww = 1; ww < 4; ++ww) s += lStat[ww*64 + t];
    lStat[320 + t] = s;
  }
  __syncthreads();   // P + xv + sums all visible

  // ---- Phase 3: PV ----
  f32x4 accO[4][4];
  for (int i = 0; i < 4; ++i) for (int j = 0; j < 4; ++j)
    for (int z = 0; z < 4; ++z) accO[i][j][z] = 0.f;
  for (int ks = 0; ks < 4; ++ks){
    int kb = w*128 + ks*32;
    short8 aP[4];
    for (int i = 0; i < 4; ++i)
      aP[i] = *(const short8*)&lP[(i*16 + lane16)*SEQ + kb + quad*8];
    for (int j = 0; j < 4; ++j){
      short8 bV = *(const short8*)&lXv[(j*16 + lane16)*SEQ + kb + quad*8];
      for (int i = 0; i < 4; ++i)
        accO[i][j] = __builtin_amdgcn_mfma_f32_16x16x32_bf16(aP[i], bV, accO[i][j], 0, 0, 0);
    }
  }
  __syncthreads();   // all reads of lP done before overwrite
  float* red = (float*)lP;
  for (int i = 0; i < 4; ++i) for (int j = 0; j < 4; ++j) for (int r = 0; r < 4; ++r)
    red[w*4096 + (i*16 + quad*4 + r)*64 + (j*16 + lane16)] = accO[i][j][r];
  __syncthreads();
  for (int z = t; z < 4096; z += 256){
    int row = z >> 6, col = z & 63;
    float v = red[z] + red[4096 + z] + red[8192 + z] + red[12288 + z];
    v /= lStat[320 + row];
    out[(rowbase + n0 + row)*DIM + h*HD + col] = v;
  }
}

// ---------------- launcher ----------------
extern "C" void kernel_launch(void* const* d_in, const int* in_sizes, int n_in,
                              void* d_out, int out_size, void* d_ws, size_t ws_size,
                              hipStream_t stream){
  const float* x = (const float*)d_in[0];
  const float* Q = (const float*)d_in[1];
  const float* V = (const float*)d_in[2];
  float* out = (float*)d_out;

  char* ws = (char*)d_ws;
  size_t off = 0;
  auto alloc = [&](size_t bytes) -> void* {
    void* p = ws + off;
    off += (bytes + 255) & ~(size_t)255;
    return p;
  };
  unsigned short* xh  = (unsigned short*)alloc((size_t)ROWS*DIM*2);       // 25.2 MB
  unsigned short* xl  = (unsigned short*)alloc((size_t)ROWS*DIM*2);       // 25.2 MB
  unsigned short* qth = (unsigned short*)alloc((size_t)NH*DIM*DIM*2);     // 14.2 MB
  unsigned short* qtl = (unsigned short*)alloc((size_t)NH*DIM*DIM*2);     // 14.2 MB
  unsigned short* vt  = (unsigned short*)alloc((size_t)NH*HD*DIM*2);      //  1.2 MB
  unsigned short* xvT = (unsigned short*)alloc((size_t)B_SZ*NH*HD*SEQ*2); // 25.2 MB
  unsigned short* qh  = (unsigned short*)alloc((size_t)ROWS*DIM*2);       // 25.2 MB
  unsigned short* ql  = (unsigned short*)alloc((size_t)ROWS*DIM*2);       // 25.2 MB
  // total ~155.6 MB

  int n4 = ROWS*DIM/4;                                  // 3,145,728
  k_split4<<<n4/256, 256, 0, stream>>>(x, xh, xl, n4);
  k_transQ<<<dim3(DIM/32, DIM/32, NH), 256, 0, stream>>>(Q, qth, qtl);
  k_transV<<<dim3(DIM/32, HD/32, NH), 256, 0, stream>>>(V, vt);
  k_gemm_xv<<<dim3(4, B_SZ, NH), 256, 0, stream>>>(xh, vt, xvT);

  for (int h = 0; h < NH; ++h){
    k_gemm_q<<<dim3(ROWS/128, DIM/128), 256, 0, stream>>>(
        xh, xl, qth + (size_t)h*DIM*DIM, qtl + (size_t)h*DIM*DIM, qh, ql);
    k_attn<<<dim3(SEQ/64, B_SZ), 256, 0, stream>>>(qh, ql, xh, xl, xvT, out, h);
  }
}

// Round 3
// 1916.179 us; speedup vs baseline: 1.4165x; 1.3624x over previous
//
#include <hip/hip_runtime.h>
#include <stdint.h>

// Problem constants
#define B_SZ 32
#define SEQ  512
#define DIM  768
#define NH   12
#define HD   64
#define ROWS (B_SZ*SEQ)   // 16384

typedef __attribute__((ext_vector_type(4))) float f32x4;
typedef __attribute__((ext_vector_type(8))) short short8;

// async global->LDS, 16B per lane; LDS dest = wave-uniform base + lane*16
#define GLOAD_LDS16(gaddr, laddr) \
  __builtin_amdgcn_global_load_lds((const __attribute__((address_space(1))) void*)(gaddr), \
                                   (__attribute__((address_space(3))) void*)(laddr), 16, 0, 0)

__device__ __forceinline__ unsigned short f2bf(float f){
  uint32_t x = __float_as_uint(f);
  uint32_t r = (x + 0x7fffu + ((x >> 16) & 1u)) >> 16;   // RNE
  return (unsigned short)r;
}
__device__ __forceinline__ float bf2f(unsigned short u){
  return __uint_as_float(((uint32_t)u) << 16);
}

// ---------------- prep kernels ----------------
__global__ void k_split4(const float* __restrict__ x,
                         unsigned short* __restrict__ xh,
                         unsigned short* __restrict__ xl, int n4){
  int i = blockIdx.x * 256 + threadIdx.x;
  if (i >= n4) return;
  float4 v = ((const float4*)x)[i];
  ushort4 h, l;
  h.x = f2bf(v.x); l.x = f2bf(v.x - bf2f(h.x));
  h.y = f2bf(v.y); l.y = f2bf(v.y - bf2f(h.y));
  h.z = f2bf(v.z); l.z = f2bf(v.z - bf2f(h.z));
  h.w = f2bf(v.w); l.w = f2bf(v.w - bf2f(h.w));
  ((ushort4*)xh)[i] = h;
  ((ushort4*)xl)[i] = l;
}

// QT[h][e][d] = split(Q[h][d][e]) — LDS-tiled transpose, both sides coalesced
__global__ __launch_bounds__(256) void k_transQ(const float* __restrict__ Q,
                         unsigned short* __restrict__ qth,
                         unsigned short* __restrict__ qtl){
  __shared__ float tile[32][33];
  int h = blockIdx.z;
  int d0 = blockIdx.x * 32;
  int e0 = blockIdx.y * 32;
  int tx = threadIdx.x & 31, ty = threadIdx.x >> 5;  // 32 x 8
  const float* Qh = Q + (size_t)h * DIM * DIM;
  for (int i = 0; i < 4; ++i)
    tile[ty + i*8][tx] = Qh[(size_t)(d0 + ty + i*8) * DIM + e0 + tx];
  __syncthreads();
  for (int i = 0; i < 4; ++i){
    float v = tile[tx][ty + i*8];
    size_t o = ((size_t)h * DIM + e0 + ty + i*8) * DIM + d0 + tx;
    unsigned short hi = f2bf(v);
    qth[o] = hi;
    qtl[o] = f2bf(v - bf2f(hi));
  }
}

// Vt[h][e][d] = bf16(V[h][d][e]) — LDS-tiled transpose
__global__ __launch_bounds__(256) void k_transV(const float* __restrict__ V,
                         unsigned short* __restrict__ vt){
  __shared__ float tile[32][33];
  int h = blockIdx.z;
  int d0 = blockIdx.x * 32;
  int e0 = blockIdx.y * 32;
  int tx = threadIdx.x & 31, ty = threadIdx.x >> 5;
  const float* Vh = V + (size_t)h * DIM * HD;
  for (int i = 0; i < 4; ++i)
    tile[ty + i*8][tx] = Vh[(size_t)(d0 + ty + i*8) * HD + e0 + tx];
  __syncthreads();
  for (int i = 0; i < 4; ++i)
    vt[((size_t)h * HD + e0 + ty + i*8) * DIM + d0 + tx] = f2bf(tile[tx][ty + i*8]);
}

// ---------------- xV GEMM (plain bf16) ----------------
__global__ __launch_bounds__(256) void k_gemm_xv(
    const unsigned short* __restrict__ xh,
    const unsigned short* __restrict__ vt,
    unsigned short* __restrict__ xvT){
  __shared__ __align__(16) unsigned short lA[128*32];
  __shared__ __align__(16) unsigned short lB[64*32];
  __shared__ __align__(16) unsigned short lOut[64*128];
  int t = threadIdx.x, w = t >> 6, l = t & 63;
  int lane16 = l & 15, quad = l >> 4;
  int b = blockIdx.y, h = blockIdx.z;
  int m0 = blockIdx.x * 128;
  const unsigned short* vth = vt + (size_t)h * HD * DIM;
  f32x4 acc[2][4];
  for (int i = 0; i < 2; ++i) for (int j = 0; j < 4; ++j)
    for (int z = 0; z < 4; ++z) acc[i][j][z] = 0.f;

  for (int kt = 0; kt < DIM/32; ++kt){
    int k0 = kt * 32;
    __syncthreads();
    for (int rep = 0; rep < 2; ++rep){
      int id = t + rep * 256;
      int row = id >> 2, ko = (id & 3) * 8;
      GLOAD_LDS16(&xh[((size_t)(b*SEQ + m0 + row))*DIM + k0 + ko],
                  &lA[(rep*256 + w*64) * 8]);
    }
    { int row = t >> 2, ko = (t & 3) * 8;
      GLOAD_LDS16(&vth[(size_t)row*DIM + k0 + ko], &lB[(w*64) * 8]); }
    __syncthreads();
    short8 a[2];
    for (int i = 0; i < 2; ++i)
      a[i] = *(const short8*)&lA[(w*32 + i*16 + lane16)*32 + quad*8];
    for (int j = 0; j < 4; ++j){
      short8 bb = *(const short8*)&lB[(j*16 + lane16)*32 + quad*8];
      for (int i = 0; i < 2; ++i)
        acc[i][j] = __builtin_amdgcn_mfma_f32_16x16x32_bf16(a[i], bb, acc[i][j], 0, 0, 0);
    }
  }
  __syncthreads();
  for (int i = 0; i < 2; ++i) for (int j = 0; j < 4; ++j) for (int r = 0; r < 4; ++r){
    int col = j*16 + lane16;
    int n  = w*32 + i*16 + quad*4 + r;
    lOut[col*128 + n] = f2bf(acc[i][j][r]);
  }
  __syncthreads();
  for (int rep = 0; rep < 4; ++rep){
    int id = t + rep*256;
    int e = id >> 4, no = (id & 15) * 8;
    *(int4*)&xvT[((size_t)(b*NH + h)*HD + e)*SEQ + m0 + no] = *(const int4*)&lOut[e*128 + no];
  }
}

// ---------------- q projection (split 3-pass) ----------------
__global__ __launch_bounds__(256) void k_gemm_q(
    const unsigned short* __restrict__ xh, const unsigned short* __restrict__ xl,
    const unsigned short* __restrict__ bth, const unsigned short* __restrict__ btl,
    unsigned short* __restrict__ qh, unsigned short* __restrict__ ql){
  __shared__ __align__(16) unsigned short lA[2][128*32];
  __shared__ __align__(16) unsigned short lB[2][128*32];
  int t = threadIdx.x, w = t >> 6, l = t & 63;
  int lane16 = l & 15, quad = l >> 4;
  int m0 = blockIdx.x * 128, n0 = blockIdx.y * 128;
  int wr = (w >> 1) * 64, wc = (w & 1) * 64;
  f32x4 acc[4][4];
  for (int i = 0; i < 4; ++i) for (int j = 0; j < 4; ++j)
    for (int z = 0; z < 4; ++z) acc[i][j][z] = 0.f;

  for (int kt = 0; kt < DIM/32; ++kt){
    int k0 = kt * 32;
    __syncthreads();
    for (int rep = 0; rep < 2; ++rep){
      int id = t + rep * 256;
      int row = id >> 2, ko = (id & 3) * 8;
      int lb = (rep*256 + w*64) * 8;
      GLOAD_LDS16(&xh [(size_t)(m0+row)*DIM + k0 + ko], &lA[0][lb]);
      GLOAD_LDS16(&xl [(size_t)(m0+row)*DIM + k0 + ko], &lA[1][lb]);
      GLOAD_LDS16(&bth[(size_t)(n0+row)*DIM + k0 + ko], &lB[0][lb]);
      GLOAD_LDS16(&btl[(size_t)(n0+row)*DIM + k0 + ko], &lB[1][lb]);
    }
    __syncthreads();
    short8 aH[4], aL[4];
    for (int i = 0; i < 4; ++i){
      int r = wr + i*16 + lane16;
      aH[i] = *(const short8*)&lA[0][r*32 + quad*8];
      aL[i] = *(const short8*)&lA[1][r*32 + quad*8];
    }
    for (int j = 0; j < 4; ++j){
      int c = wc + j*16 + lane16;
      short8 bH = *(const short8*)&lB[0][c*32 + quad*8];
      short8 bL = *(const short8*)&lB[1][c*32 + quad*8];
      for (int i = 0; i < 4; ++i){
        acc[i][j] = __builtin_amdgcn_mfma_f32_16x16x32_bf16(aL[i], bH, acc[i][j], 0, 0, 0);
        acc[i][j] = __builtin_amdgcn_mfma_f32_16x16x32_bf16(aH[i], bL, acc[i][j], 0, 0, 0);
        acc[i][j] = __builtin_amdgcn_mfma_f32_16x16x32_bf16(aH[i], bH, acc[i][j], 0, 0, 0);
      }
    }
  }
  for (int i = 0; i < 4; ++i) for (int j = 0; j < 4; ++j) for (int r = 0; r < 4; ++r){
    int row = m0 + wr + i*16 + quad*4 + r;
    int col = n0 + wc + j*16 + lane16;
    float v = acc[i][j][r];
    unsigned short hh = f2bf(v);
    size_t o = (size_t)row*DIM + col;
    qh[o] = hh;
    ql[o] = f2bf(v - bf2f(hh));
  }
}

// ---------------- fused attention per head ----------------
// grid (32 b, 8 nt)  [b-major: the 8 blocks sharing batch b land on one XCD]
// block 256 (4 waves). BM=64 q-rows, full 512 keys.
// Double-buffered staging of keys+q (1 block/CU -> explicit overlap needed).
// LDS pool layout (shorts):
//   phase 1: keys[buf][hl]: buf*32768 + hl*16384  (128 KB)
//            q[buf][hl]:    65536 + buf*4096 + hl*2048 (16 KB)  -> total 144 KB
//   phase 2/3 (after barrier, keys/q dead):
//            lP : rows 64, stride 520, base 0        (66.6 KB)
//            lXv: rows 64, stride 520, base 34816    (66.6 KB)
//            red: float[16384] alias base 0 (after PV barrier)
#define SEQP 520
__global__ __launch_bounds__(256) void k_attn(
    const unsigned short* __restrict__ qh, const unsigned short* __restrict__ ql,
    const unsigned short* __restrict__ xh, const unsigned short* __restrict__ xl,
    const unsigned short* __restrict__ xvT,
    float* __restrict__ out, int h){
  __shared__ __align__(16) unsigned short lsh[73728];   // 144 KB
  __shared__ float lStat[4*64 + 64 + 64];               // 1.5 KB

  int t = threadIdx.x, w = t >> 6, l = t & 63;
  int lane16 = l & 15, quad = l >> 4;
  int b = blockIdx.x, nt = blockIdx.y;
  int n0 = nt * 64;
  size_t rowbase = (size_t)b * SEQ;

  f32x4 accS[4][8];
  for (int i = 0; i < 4; ++i) for (int j = 0; j < 8; ++j)
    for (int z = 0; z < 4; ++z) accS[i][j][z] = 0.f;

  // stage tile kt into buffer kt&1
  auto stage = [&](int kt){
    int k0 = kt * 32, bb = kt & 1;
    int qb = 65536 + bb*4096;
    { int row = t >> 2, ko = (t & 3) * 8;   // q 64x32 hi+lo
      GLOAD_LDS16(&qh[(rowbase + n0 + row)*DIM + k0 + ko], &lsh[qb + w*512]);
      GLOAD_LDS16(&ql[(rowbase + n0 + row)*DIM + k0 + ko], &lsh[qb + 2048 + w*512]); }
    int kb = bb*32768;
    for (int rep = 0; rep < 8; ++rep){      // keys 512x32 hi+lo
      int id = t + rep * 256;
      int row = id >> 2, ko = (id & 3) * 8;
      int lb = (rep*256 + w*64) * 8;
      GLOAD_LDS16(&xh[(rowbase + row)*DIM + k0 + ko], &lsh[kb + lb]);
      GLOAD_LDS16(&xl[(rowbase + row)*DIM + k0 + ko], &lsh[kb + 16384 + lb]);
    }
  };

  // ---- Phase 1: scores, double-buffered ----
  stage(0);
  for (int kt = 0; kt < DIM/32; ++kt){
    __syncthreads();                 // drains staging of buffer kt&1
    if (kt + 1 < DIM/32) stage(kt + 1);   // prefetch in flight during compute
    int bb = kt & 1;
    int qb = 65536 + bb*4096, kb = bb*32768;
    short8 aH[4], aL[4];
    for (int i = 0; i < 4; ++i){
      int r = i*16 + lane16;
      aH[i] = *(const short8*)&lsh[qb + r*32 + quad*8];
      aL[i] = *(const short8*)&lsh[qb + 2048 + r*32 + quad*8];
    }
    for (int j = 0; j < 8; ++j){
      int c = w*128 + j*16 + lane16;
      short8 bH = *(const short8*)&lsh[kb + c*32 + quad*8];
      short8 bL = *(const short8*)&lsh[kb + 16384 + c*32 + quad*8];
      for (int i = 0; i < 4; ++i){
        accS[i][j] = __builtin_amdgcn_mfma_f32_16x16x32_bf16(aL[i], bH, accS[i][j], 0, 0, 0);
        accS[i][j] = __builtin_amdgcn_mfma_f32_16x16x32_bf16(aH[i], bL, accS[i][j], 0, 0, 0);
        accS[i][j] = __builtin_amdgcn_mfma_f32_16x16x32_bf16(aH[i], bH, accS[i][j], 0, 0, 0);
      }
    }
  }
  __syncthreads();   // all reads of keys/q done; LDS pool is repurposed below

  // stage xvT[b,h] (64 e-rows x 512) into padded lXv rows (one wave-instr per row,
  // so pads between rows don't break the lane-linear LDS mapping)
  const int XVB = 34816;
  for (int it = 0; it < 16; ++it){
    int e = it*4 + w;
    GLOAD_LDS16(&xvT[((size_t)(b*NH + h)*HD + e)*SEQ + l*8], &lsh[XVB + e*SEQP]);
  }

  // ---- Phase 2: softmax ----
  float rmx[4][4];
  for (int i = 0; i < 4; ++i) for (int r = 0; r < 4; ++r){
    float m = accS[i][0][r];
    for (int j = 1; j < 8; ++j) m = fmaxf(m, accS[i][j][r]);
    for (int d = 1; d < 16; d <<= 1) m = fmaxf(m, __shfl_xor(m, d, 64));
    rmx[i][r] = m;
  }
  if (lane16 == 0)
    for (int i = 0; i < 4; ++i) for (int r = 0; r < 4; ++r)
      lStat[w*64 + i*16 + quad*4 + r] = rmx[i][r];
  __syncthreads();
  if (t < 64){
    float m = lStat[t];
    for (int ww = 1; ww < 4; ++ww) m = fmaxf(m, lStat[ww*64 + t]);
    lStat[256 + t] = m;
  }
  __syncthreads();
  float rsum[4][4];
  for (int i = 0; i < 4; ++i) for (int r = 0; r < 4; ++r){
    float g = lStat[256 + i*16 + quad*4 + r];
    float s = 0.f;
    for (int j = 0; j < 8; ++j){
      float p = __expf(accS[i][j][r] - g);
      s += p;
      lsh[(i*16 + quad*4 + r)*SEQP + (w*128 + j*16 + lane16)] = f2bf(p);
    }
    for (int d = 1; d < 16; d <<= 1) s += __shfl_xor(s, d, 64);
    rsum[i][r] = s;
  }
  if (lane16 == 0)
    for (int i = 0; i < 4; ++i) for (int r = 0; r < 4; ++r)
      lStat[w*64 + i*16 + quad*4 + r] = rsum[i][r];
  __syncthreads();
  if (t < 64){
    float s = lStat[t];
    for (int ww = 1; ww < 4; ++ww) s += lStat[ww*64 + t];
    lStat[320 + t] = s;
  }
  __syncthreads();   // P + xv + sums all visible

  // ---- Phase 3: PV ----
  f32x4 accO[4][4];
  for (int i = 0; i < 4; ++i) for (int j = 0; j < 4; ++j)
    for (int z = 0; z < 4; ++z) accO[i][j][z] = 0.f;
  for (int ks = 0; ks < 4; ++ks){
    int kb = w*128 + ks*32;
    short8 aP[4];
    for (int i = 0; i < 4; ++i)
      aP[i] = *(const short8*)&lsh[(i*16 + lane16)*SEQP + kb + quad*8];
    for (int j = 0; j < 4; ++j){
      short8 bV = *(const short8*)&lsh[XVB + (j*16 + lane16)*SEQP + kb + quad*8];
      for (int i = 0; i < 4; ++i)
        accO[i][j] = __builtin_amdgcn_mfma_f32_16x16x32_bf16(aP[i], bV, accO[i][j], 0, 0, 0);
    }
  }
  __syncthreads();   // all reads of lP done before overwrite
  float* red = (float*)lsh;
  for (int i = 0; i < 4; ++i) for (int j = 0; j < 4; ++j) for (int r = 0; r < 4; ++r)
    red[w*4096 + (i*16 + quad*4 + r)*64 + (j*16 + lane16)] = accO[i][j][r];
  __syncthreads();
  for (int z = t; z < 4096; z += 256){
    int row = z >> 6, col = z & 63;
    float v = red[z] + red[4096 + z] + red[8192 + z] + red[12288 + z];
    v /= lStat[320 + row];
    out[(rowbase + n0 + row)*DIM + h*HD + col] = v;
  }
}

// ---------------- launcher ----------------
extern "C" void kernel_launch(void* const* d_in, const int* in_sizes, int n_in,
                              void* d_out, int out_size, void* d_ws, size_t ws_size,
                              hipStream_t stream){
  const float* x = (const float*)d_in[0];
  const float* Q = (const float*)d_in[1];
  const float* V = (const float*)d_in[2];
  float* out = (float*)d_out;

  char* ws = (char*)d_ws;
  size_t off = 0;
  auto alloc = [&](size_t bytes) -> void* {
    void* p = ws + off;
    off += (bytes + 255) & ~(size_t)255;
    return p;
  };
  unsigned short* xh  = (unsigned short*)alloc((size_t)ROWS*DIM*2);
  unsigned short* xl  = (unsigned short*)alloc((size_t)ROWS*DIM*2);
  unsigned short* qth = (unsigned short*)alloc((size_t)NH*DIM*DIM*2);
  unsigned short* qtl = (unsigned short*)alloc((size_t)NH*DIM*DIM*2);
  unsigned short* vt  = (unsigned short*)alloc((size_t)NH*HD*DIM*2);
  unsigned short* xvT = (unsigned short*)alloc((size_t)B_SZ*NH*HD*SEQ*2);
  unsigned short* qh  = (unsigned short*)alloc((size_t)ROWS*DIM*2);
  unsigned short* ql  = (unsigned short*)alloc((size_t)ROWS*DIM*2);
  // total ~155.6 MB

  int n4 = ROWS*DIM/4;
  k_split4<<<n4/256, 256, 0, stream>>>(x, xh, xl, n4);
  k_transQ<<<dim3(DIM/32, DIM/32, NH), 256, 0, stream>>>(Q, qth, qtl);
  k_transV<<<dim3(DIM/32, HD/32, NH), 256, 0, stream>>>(V, vt);
  k_gemm_xv<<<dim3(4, B_SZ, NH), 256, 0, stream>>>(xh, vt, xvT);

  for (int h = 0; h < NH; ++h){
    k_gemm_q<<<dim3(ROWS/128, DIM/128), 256, 0, stream>>>(
        xh, xl, qth + (size_t)h*DIM*DIM, qtl + (size_t)h*DIM*DIM, qh, ql);
    k_attn<<<dim3(B_SZ, SEQ/64), 256, 0, stream>>>(qh, ql, xh, xl, xvT, out, h);
  }
}

// Round 5
// 1828.158 us; speedup vs baseline: 1.4847x; 1.0481x over previous
//
#include <hip/hip_runtime.h>
#include <stdint.h>

// Problem constants
#define B_SZ 32
#define SEQ  512
#define DIM  768
#define NH   12
#define HD   64
#define ROWS (B_SZ*SEQ)   // 16384

typedef __attribute__((ext_vector_type(4))) float f32x4;
typedef __attribute__((ext_vector_type(8))) _Float16 half8;

// async global->LDS, 16B per lane; LDS dest = wave-uniform base + lane*16
#define GLOAD_LDS16(gaddr, laddr) \
  __builtin_amdgcn_global_load_lds((const __attribute__((address_space(1))) void*)(gaddr), \
                                   (__attribute__((address_space(3))) void*)(laddr), 16, 0, 0)

__device__ __forceinline__ unsigned short h2u(_Float16 h){
  union { _Float16 h; unsigned short u; } c; c.h = h; return c.u;
}
__device__ __forceinline__ unsigned short f2hu(float f){
  return h2u((_Float16)f);
}

// ---------------- prep kernels ----------------
// x fp32 -> fp16 hi + fp16 lo residual, 4 elems/thread
__global__ void k_split(const float* __restrict__ x,
                        unsigned short* __restrict__ xh,
                        unsigned short* __restrict__ xl, int n4){
  int i = blockIdx.x * 256 + threadIdx.x;
  if (i >= n4) return;
  float4 v = ((const float4*)x)[i];
  ushort4 h, l;
  _Float16 t;
  t = (_Float16)v.x; h.x = h2u(t); l.x = f2hu(v.x - (float)t);
  t = (_Float16)v.y; h.y = h2u(t); l.y = f2hu(v.y - (float)t);
  t = (_Float16)v.z; h.z = h2u(t); l.z = f2hu(v.z - (float)t);
  t = (_Float16)v.w; h.w = h2u(t); l.w = f2hu(v.w - (float)t);
  ((ushort4*)xh)[i] = h;
  ((ushort4*)xl)[i] = l;
}

// QT[h][e][d] = split(Q[h][d][e]) — LDS-tiled transpose, both sides coalesced
__global__ __launch_bounds__(256) void k_transQ(const float* __restrict__ Q,
                         unsigned short* __restrict__ qth,
                         unsigned short* __restrict__ qtl){
  __shared__ float tile[32][33];
  int h = blockIdx.z;
  int d0 = blockIdx.x * 32;
  int e0 = blockIdx.y * 32;
  int tx = threadIdx.x & 31, ty = threadIdx.x >> 5;  // 32 x 8
  const float* Qh = Q + (size_t)h * DIM * DIM;
  for (int i = 0; i < 4; ++i)
    tile[ty + i*8][tx] = Qh[(size_t)(d0 + ty + i*8) * DIM + e0 + tx];
  __syncthreads();
  for (int i = 0; i < 4; ++i){
    float v = tile[tx][ty + i*8];
    size_t o = ((size_t)h * DIM + e0 + ty + i*8) * DIM + d0 + tx;
    _Float16 hi = (_Float16)v;
    qth[o] = h2u(hi);
    qtl[o] = f2hu(v - (float)hi);
  }
}

// Vt[h][e][d] = fp16(V[h][d][e]) — LDS-tiled transpose
__global__ __launch_bounds__(256) void k_transV(const float* __restrict__ V,
                         unsigned short* __restrict__ vt16){
  __shared__ float tile[32][33];
  int h = blockIdx.z;
  int d0 = blockIdx.x * 32;
  int e0 = blockIdx.y * 32;
  int tx = threadIdx.x & 31, ty = threadIdx.x >> 5;
  const float* Vh = V + (size_t)h * DIM * HD;
  for (int i = 0; i < 4; ++i)
    tile[ty + i*8][tx] = Vh[(size_t)(d0 + ty + i*8) * HD + e0 + tx];
  __syncthreads();
  for (int i = 0; i < 4; ++i)
    vt16[((size_t)h * HD + e0 + ty + i*8) * DIM + d0 + tx] = f2hu(tile[tx][ty + i*8]);
}

// ---------------- xV GEMM (fp16 single-pass; post-softmax tolerance) ----------------
// xvT[(b*NH+h)*64 + e][n] = sum_d x[b,n,d] * V[h,d,e]
// grid: (4 mtiles, 32 b, 12 h), block 256. tile 128n x 64e, BK=64.
__global__ __launch_bounds__(256) void k_gemm_xv(
    const unsigned short* __restrict__ xh,
    const unsigned short* __restrict__ vt16,
    unsigned short* __restrict__ xvT){
  __shared__ __align__(16) unsigned short lA[128*64];
  __shared__ __align__(16) unsigned short lB[64*64];
  __shared__ __align__(16) unsigned short lOut[64*128];
  int t = threadIdx.x, w = t >> 6, l = t & 63;
  int lane16 = l & 15, quad = l >> 4;
  int b = blockIdx.y, h = blockIdx.z;
  int m0 = blockIdx.x * 128;
  const unsigned short* vth = vt16 + (size_t)h * HD * DIM;
  f32x4 acc[2][4];
  for (int i = 0; i < 2; ++i) for (int j = 0; j < 4; ++j)
    for (int z = 0; z < 4; ++z) acc[i][j][z] = 0.f;

  for (int kt = 0; kt < DIM/64; ++kt){
    int k0 = kt * 64;
    __syncthreads();
    for (int rep = 0; rep < 4; ++rep){
      int id = t + rep * 256;              // 0..1023
      int row = id >> 3, ko = (id & 7) * 8;
      GLOAD_LDS16(&xh[((size_t)(b*SEQ + m0 + row))*DIM + k0 + ko],
                  &lA[(rep*256 + w*64) * 8]);
    }
    for (int rep = 0; rep < 2; ++rep){     // 64x64
      int id = t + rep * 256;
      int row = id >> 3, ko = (id & 7) * 8;
      GLOAD_LDS16(&vth[(size_t)row*DIM + k0 + ko], &lB[(rep*256 + w*64) * 8]);
    }
    __syncthreads();
    for (int ks = 0; ks < 2; ++ks){
      half8 a[2];
      for (int i = 0; i < 2; ++i)
        a[i] = *(const half8*)&lA[(w*32 + i*16 + lane16)*64 + ks*32 + quad*8];
      for (int j = 0; j < 4; ++j){
        half8 bb = *(const half8*)&lB[(j*16 + lane16)*64 + ks*32 + quad*8];
        for (int i = 0; i < 2; ++i)
          acc[i][j] = __builtin_amdgcn_mfma_f32_16x16x32_f16(a[i], bb, acc[i][j], 0, 0, 0);
      }
    }
  }
  // epilogue: transpose through LDS, contiguous row stores
  __syncthreads();
  for (int i = 0; i < 2; ++i) for (int j = 0; j < 4; ++j) for (int r = 0; r < 4; ++r){
    int col = j*16 + lane16;
    int n  = w*32 + i*16 + quad*4 + r;
    lOut[col*128 + n] = f2hu(acc[i][j][r]);
  }
  __syncthreads();
  for (int rep = 0; rep < 4; ++rep){
    int id = t + rep*256;                  // 0..1023 int4s
    int e = id >> 4, no = (id & 15) * 8;
    *(int4*)&xvT[((size_t)(b*NH + h)*HD + e)*SEQ + m0 + no] = *(const int4*)&lOut[e*128 + no];
  }
}

// ---------------- q projection (split-fp16, 3-pass) ----------------
// q[bn][e] = sum_d x[bn][d] * Q_h[d][e]; grid (128 Mtiles, 6 Ntiles).
// tile 128x128, BK=64, single-buffered 64 KB LDS -> 2 blocks/CU (m97-style).
__global__ __launch_bounds__(256, 2) void k_gemm_q(
    const unsigned short* __restrict__ xh, const unsigned short* __restrict__ xl,
    const unsigned short* __restrict__ bth, const unsigned short* __restrict__ btl,
    unsigned short* __restrict__ qh, unsigned short* __restrict__ ql){
  __shared__ __align__(16) unsigned short lA[2][128*64];   // [hl] 32 KB
  __shared__ __align__(16) unsigned short lB[2][128*64];   // [hl] 32 KB
  int t = threadIdx.x, w = t >> 6, l = t & 63;
  int lane16 = l & 15, quad = l >> 4;
  int m0 = blockIdx.x * 128, n0 = blockIdx.y * 128;
  int wr = (w >> 1) * 64, wc = (w & 1) * 64;
  f32x4 acc[4][4];
  for (int i = 0; i < 4; ++i) for (int j = 0; j < 4; ++j)
    for (int z = 0; z < 4; ++z) acc[i][j][z] = 0.f;

  for (int kt = 0; kt < DIM/64; ++kt){
    int k0 = kt * 64;
    __syncthreads();                       // previous compute's LDS reads done
    for (int rep = 0; rep < 4; ++rep){
      int id = t + rep * 256;              // 0..1023
      int row = id >> 3, ko = (id & 7) * 8;
      int lb = (rep*256 + w*64) * 8;
      GLOAD_LDS16(&xh [(size_t)(m0+row)*DIM + k0 + ko], &lA[0][lb]);
      GLOAD_LDS16(&xl [(size_t)(m0+row)*DIM + k0 + ko], &lA[1][lb]);
      GLOAD_LDS16(&bth[(size_t)(n0+row)*DIM + k0 + ko], &lB[0][lb]);
      GLOAD_LDS16(&btl[(size_t)(n0+row)*DIM + k0 + ko], &lB[1][lb]);
    }
    __syncthreads();                       // drain staging
    for (int ks = 0; ks < 2; ++ks){
      half8 aH[4], aL[4];
      for (int i = 0; i < 4; ++i){
        int r = wr + i*16 + lane16;
        aH[i] = *(const half8*)&lA[0][r*64 + ks*32 + quad*8];
        aL[i] = *(const half8*)&lA[1][r*64 + ks*32 + quad*8];
      }
      for (int j = 0; j < 4; ++j){
        int c = wc + j*16 + lane16;
        half8 bH = *(const half8*)&lB[0][c*64 + ks*32 + quad*8];
        half8 bL = *(const half8*)&lB[1][c*64 + ks*32 + quad*8];
        for (int i = 0; i < 4; ++i){
          acc[i][j] = __builtin_amdgcn_mfma_f32_16x16x32_f16(aL[i], bH, acc[i][j], 0, 0, 0);
          acc[i][j] = __builtin_amdgcn_mfma_f32_16x16x32_f16(aH[i], bL, acc[i][j], 0, 0, 0);
          acc[i][j] = __builtin_amdgcn_mfma_f32_16x16x32_f16(aH[i], bH, acc[i][j], 0, 0, 0);
        }
      }
    }
  }
  for (int i = 0; i < 4; ++i) for (int j = 0; j < 4; ++j) for (int r = 0; r < 4; ++r){
    int row = m0 + wr + i*16 + quad*4 + r;
    int col = n0 + wc + j*16 + lane16;
    float v = acc[i][j][r];
    _Float16 hh = (_Float16)v;
    size_t o = (size_t)row*DIM + col;
    qh[o] = h2u(hh);
    ql[o] = f2hu(v - (float)hh);
  }
}

// ---------------- fused attention per head ----------------
// grid (32 b, 8 nt) b-major (XCD L2 sharing of keys). block 256 (4 waves).
// BM=64 q-rows, full 512 keys, split-fp16 3-pass scores, BK=32 dbuf staging.
// LDS pool (shorts):
//   phase 1: keys[bb][hl]: bb*32768 + hl*16384 (128 KB); q[bb][hl]: 65536+bb*4096+hl*2048 (16 KB)
//   phase 2/3: lP rows 64 stride 520 @0; lXv rows 64 stride 520 @34816;
//              red float[16384] alias @0 after PV barrier
#define SEQP 520
__global__ __launch_bounds__(256) void k_attn(
    const unsigned short* __restrict__ qh, const unsigned short* __restrict__ ql,
    const unsigned short* __restrict__ xh, const unsigned short* __restrict__ xl,
    const unsigned short* __restrict__ xvT,
    float* __restrict__ out, int h){
  __shared__ __align__(16) unsigned short lsh[73728];   // 144 KB
  __shared__ float lStat[4*64 + 64 + 64];

  int t = threadIdx.x, w = t >> 6, l = t & 63;
  int lane16 = l & 15, quad = l >> 4;
  int b = blockIdx.x, nt = blockIdx.y;
  int n0 = nt * 64;
  size_t rowbase = (size_t)b * SEQ;

  f32x4 accS[4][8];
  for (int i = 0; i < 4; ++i) for (int j = 0; j < 8; ++j)
    for (int z = 0; z < 4; ++z) accS[i][j][z] = 0.f;

  auto stage = [&](int kt){
    int k0 = kt * 32, bb = kt & 1;
    int qb = 65536 + bb*4096;
    { int row = t >> 2, ko = (t & 3) * 8;   // q 64x32 hi+lo
      GLOAD_LDS16(&qh[(rowbase + n0 + row)*DIM + k0 + ko], &lsh[qb + w*512]);
      GLOAD_LDS16(&ql[(rowbase + n0 + row)*DIM + k0 + ko], &lsh[qb + 2048 + w*512]); }
    int kb = bb*32768;
    for (int rep = 0; rep < 8; ++rep){      // keys 512x32 hi+lo
      int id = t + rep * 256;
      int row = id >> 2, ko = (id & 3) * 8;
      int lb = (rep*256 + w*64) * 8;
      GLOAD_LDS16(&xh[(rowbase + row)*DIM + k0 + ko], &lsh[kb + lb]);
      GLOAD_LDS16(&xl[(rowbase + row)*DIM + k0 + ko], &lsh[kb + 16384 + lb]);
    }
  };

  // ---- Phase 1: scores, double-buffered, 3-pass split ----
  stage(0);
  for (int kt = 0; kt < DIM/32; ++kt){
    __syncthreads();                 // drains staging of buffer kt&1
    if (kt + 1 < DIM/32) stage(kt + 1);   // prefetch in flight during compute
    int bb = kt & 1;
    int qb = 65536 + bb*4096, kb = bb*32768;
    half8 aH[4], aL[4];
    for (int i = 0; i < 4; ++i){
      int r = i*16 + lane16;
      aH[i] = *(const half8*)&lsh[qb + r*32 + quad*8];
      aL[i] = *(const half8*)&lsh[qb + 2048 + r*32 + quad*8];
    }
    for (int j = 0; j < 8; ++j){
      int c = w*128 + j*16 + lane16;
      half8 bH = *(const half8*)&lsh[kb + c*32 + quad*8];
      half8 bL = *(const half8*)&lsh[kb + 16384 + c*32 + quad*8];
      for (int i = 0; i < 4; ++i){
        accS[i][j] = __builtin_amdgcn_mfma_f32_16x16x32_f16(aL[i], bH, accS[i][j], 0, 0, 0);
        accS[i][j] = __builtin_amdgcn_mfma_f32_16x16x32_f16(aH[i], bL, accS[i][j], 0, 0, 0);
        accS[i][j] = __builtin_amdgcn_mfma_f32_16x16x32_f16(aH[i], bH, accS[i][j], 0, 0, 0);
      }
    }
  }
  __syncthreads();   // keys/q dead; repurpose pool

  // stage xvT[b,h] rows (512 fp16 = 1024 B = one wave-instr per row; pads between rows OK)
  const int XVB = 34816;
  for (int it = 0; it < 16; ++it){
    int e = it*4 + w;
    GLOAD_LDS16(&xvT[((size_t)(b*NH + h)*HD + e)*SEQ + l*8], &lsh[XVB + e*SEQP]);
  }

  // ---- Phase 2: softmax ----
  float rmx[4][4];
  for (int i = 0; i < 4; ++i) for (int r = 0; r < 4; ++r){
    float m = accS[i][0][r];
    for (int j = 1; j < 8; ++j) m = fmaxf(m, accS[i][j][r]);
    for (int d = 1; d < 16; d <<= 1) m = fmaxf(m, __shfl_xor(m, d, 64));
    rmx[i][r] = m;
  }
  if (lane16 == 0)
    for (int i = 0; i < 4; ++i) for (int r = 0; r < 4; ++r)
      lStat[w*64 + i*16 + quad*4 + r] = rmx[i][r];
  __syncthreads();
  if (t < 64){
    float m = lStat[t];
    for (int ww = 1; ww < 4; ++ww) m = fmaxf(m, lStat[ww*64 + t]);
    lStat[256 + t] = m;
  }
  __syncthreads();
  float rsum[4][4];
  for (int i = 0; i < 4; ++i) for (int r = 0; r < 4; ++r){
    float g = lStat[256 + i*16 + quad*4 + r];
    float s = 0.f;
    for (int j = 0; j < 8; ++j){
      float p = __expf(accS[i][j][r] - g);
      s += p;
      lsh[(i*16 + quad*4 + r)*SEQP + (w*128 + j*16 + lane16)] = f2hu(p);
    }
    for (int d = 1; d < 16; d <<= 1) s += __shfl_xor(s, d, 64);
    rsum[i][r] = s;
  }
  if (lane16 == 0)
    for (int i = 0; i < 4; ++i) for (int r = 0; r < 4; ++r)
      lStat[w*64 + i*16 + quad*4 + r] = rsum[i][r];
  __syncthreads();
  if (t < 64){
    float s = lStat[t];
    for (int ww = 1; ww < 4; ++ww) s += lStat[ww*64 + t];
    lStat[320 + t] = s;
  }
  __syncthreads();   // P + xv + sums visible

  // ---- Phase 3: PV ----
  f32x4 accO[4][4];
  for (int i = 0; i < 4; ++i) for (int j = 0; j < 4; ++j)
    for (int z = 0; z < 4; ++z) accO[i][j][z] = 0.f;
  for (int ks = 0; ks < 4; ++ks){
    int kb = w*128 + ks*32;
    half8 aP[4];
    for (int i = 0; i < 4; ++i)
      aP[i] = *(const half8*)&lsh[(i*16 + lane16)*SEQP + kb + quad*8];
    for (int j = 0; j < 4; ++j){
      half8 bV = *(const half8*)&lsh[XVB + (j*16 + lane16)*SEQP + kb + quad*8];
      for (int i = 0; i < 4; ++i)
        accO[i][j] = __builtin_amdgcn_mfma_f32_16x16x32_f16(aP[i], bV, accO[i][j], 0, 0, 0);
    }
  }
  __syncthreads();
  float* red = (float*)lsh;
  for (int i = 0; i < 4; ++i) for (int j = 0; j < 4; ++j) for (int r = 0; r < 4; ++r)
    red[w*4096 + (i*16 + quad*4 + r)*64 + (j*16 + lane16)] = accO[i][j][r];
  __syncthreads();
  for (int z = t; z < 4096; z += 256){
    int row = z >> 6, col = z & 63;
    float v = red[z] + red[4096 + z] + red[8192 + z] + red[12288 + z];
    v /= lStat[320 + row];
    out[(rowbase + n0 + row)*DIM + h*HD + col] = v;
  }
}

// ---------------- launcher ----------------
extern "C" void kernel_launch(void* const* d_in, const int* in_sizes, int n_in,
                              void* d_out, int out_size, void* d_ws, size_t ws_size,
                              hipStream_t stream){
  const float* x = (const float*)d_in[0];
  const float* Q = (const float*)d_in[1];
  const float* V = (const float*)d_in[2];
  float* out = (float*)d_out;

  char* ws = (char*)d_ws;
  size_t off = 0;
  auto alloc = [&](size_t bytes) -> void* {
    void* p = ws + off;
    off += (bytes + 255) & ~(size_t)255;
    return p;
  };
  unsigned short* xh  = (unsigned short*)alloc((size_t)ROWS*DIM*2);       // 25.2 MB
  unsigned short* xl  = (unsigned short*)alloc((size_t)ROWS*DIM*2);       // 25.2 MB
  unsigned short* qth = (unsigned short*)alloc((size_t)NH*DIM*DIM*2);     // 14.2 MB
  unsigned short* qtl = (unsigned short*)alloc((size_t)NH*DIM*DIM*2);     // 14.2 MB
  unsigned short* vt  = (unsigned short*)alloc((size_t)NH*HD*DIM*2);      //  1.2 MB
  unsigned short* xvT = (unsigned short*)alloc((size_t)B_SZ*NH*HD*SEQ*2); // 25.2 MB
  unsigned short* qh  = (unsigned short*)alloc((size_t)ROWS*DIM*2);       // 25.2 MB (per-head reuse)
  unsigned short* ql  = (unsigned short*)alloc((size_t)ROWS*DIM*2);       // 25.2 MB
  // total ~155.6 MB (R0-proven size)

  int n4 = ROWS*DIM/4;
  k_split<<<n4/256, 256, 0, stream>>>(x, xh, xl, n4);
  k_transQ<<<dim3(DIM/32, DIM/32, NH), 256, 0, stream>>>(Q, qth, qtl);
  k_transV<<<dim3(DIM/32, HD/32, NH), 256, 0, stream>>>(V, vt);
  k_gemm_xv<<<dim3(4, B_SZ, NH), 256, 0, stream>>>(xh, vt, xvT);

  for (int h = 0; h < NH; ++h){
    k_gemm_q<<<dim3(ROWS/128, DIM/128), 256, 0, stream>>>(
        xh, xl, qth + (size_t)h*DIM*DIM, qtl + (size_t)h*DIM*DIM, qh, ql);
    k_attn<<<dim3(B_SZ, SEQ/64), 256, 0, stream>>>(qh, ql, xh, xl, xvT, out, h);
  }
}

// Round 6
// 1590.836 us; speedup vs baseline: 1.7062x; 1.1492x over previous
//
#include <hip/hip_runtime.h>
#include <stdint.h>

// Problem constants
#define B_SZ 32
#define SEQ  512
#define DIM  768
#define NH   12
#define HD   64
#define ROWS (B_SZ*SEQ)   // 16384

typedef __attribute__((ext_vector_type(4))) float f32x4;
typedef __attribute__((ext_vector_type(8))) _Float16 half8;

// async global->LDS, 16B per lane; LDS dest = wave-uniform base + lane*16
// (global address is per-lane arbitrary -> XOR-swizzled fetches are legal)
#define GLOAD_LDS16(gaddr, laddr) \
  __builtin_amdgcn_global_load_lds((const __attribute__((address_space(1))) void*)(gaddr), \
                                   (__attribute__((address_space(3))) void*)(laddr), 16, 0, 0)

__device__ __forceinline__ unsigned short h2u(_Float16 h){
  union { _Float16 h; unsigned short u; } c; c.h = h; return c.u;
}
__device__ __forceinline__ unsigned short f2hu(float f){
  return h2u((_Float16)f);
}

// ---------------- prep kernels ----------------
// x fp32 -> fp16 hi + fp16 lo residual, 4 elems/thread
__global__ void k_split(const float* __restrict__ x,
                        unsigned short* __restrict__ xh,
                        unsigned short* __restrict__ xl, int n4){
  int i = blockIdx.x * 256 + threadIdx.x;
  if (i >= n4) return;
  float4 v = ((const float4*)x)[i];
  ushort4 h, l;
  _Float16 t;
  t = (_Float16)v.x; h.x = h2u(t); l.x = f2hu(v.x - (float)t);
  t = (_Float16)v.y; h.y = h2u(t); l.y = f2hu(v.y - (float)t);
  t = (_Float16)v.z; h.z = h2u(t); l.z = f2hu(v.z - (float)t);
  t = (_Float16)v.w; h.w = h2u(t); l.w = f2hu(v.w - (float)t);
  ((ushort4*)xh)[i] = h;
  ((ushort4*)xl)[i] = l;
}

// QT[h][e][d] = split(Q[h][d][e]) — LDS-tiled transpose, both sides coalesced
__global__ __launch_bounds__(256) void k_transQ(const float* __restrict__ Q,
                         unsigned short* __restrict__ qth,
                         unsigned short* __restrict__ qtl){
  __shared__ float tile[32][33];
  int h = blockIdx.z;
  int d0 = blockIdx.x * 32;
  int e0 = blockIdx.y * 32;
  int tx = threadIdx.x & 31, ty = threadIdx.x >> 5;  // 32 x 8
  const float* Qh = Q + (size_t)h * DIM * DIM;
  for (int i = 0; i < 4; ++i)
    tile[ty + i*8][tx] = Qh[(size_t)(d0 + ty + i*8) * DIM + e0 + tx];
  __syncthreads();
  for (int i = 0; i < 4; ++i){
    float v = tile[tx][ty + i*8];
    size_t o = ((size_t)h * DIM + e0 + ty + i*8) * DIM + d0 + tx;
    _Float16 hi = (_Float16)v;
    qth[o] = h2u(hi);
    qtl[o] = f2hu(v - (float)hi);
  }
}

// Vt[h][e][d] = fp16(V[h][d][e]) — LDS-tiled transpose
__global__ __launch_bounds__(256) void k_transV(const float* __restrict__ V,
                         unsigned short* __restrict__ vt16){
  __shared__ float tile[32][33];
  int h = blockIdx.z;
  int d0 = blockIdx.x * 32;
  int e0 = blockIdx.y * 32;
  int tx = threadIdx.x & 31, ty = threadIdx.x >> 5;
  const float* Vh = V + (size_t)h * DIM * HD;
  for (int i = 0; i < 4; ++i)
    tile[ty + i*8][tx] = Vh[(size_t)(d0 + ty + i*8) * HD + e0 + tx];
  __syncthreads();
  for (int i = 0; i < 4; ++i)
    vt16[((size_t)h * HD + e0 + ty + i*8) * DIM + d0 + tx] = f2hu(tile[tx][ty + i*8]);
}

// ---------------- xV GEMM (fp16 single-pass, BK=32 balanced layout) ----------------
// xvT[(b*NH+h)*64 + e][n] = sum_d x[b,n,d] * V[h,d,e]
// grid: (4 mtiles, 32 b, 12 h), block 256. tile 128n x 64e.
__global__ __launch_bounds__(256) void k_gemm_xv(
    const unsigned short* __restrict__ xh,
    const unsigned short* __restrict__ vt16,
    unsigned short* __restrict__ xvT){
  __shared__ __align__(16) unsigned short lA[128*32];
  __shared__ __align__(16) unsigned short lB[64*32];
  __shared__ __align__(16) unsigned short lOut[64*128];
  int t = threadIdx.x, w = t >> 6, l = t & 63;
  int lane16 = l & 15, quad = l >> 4;
  int b = blockIdx.y, h = blockIdx.z;
  int m0 = blockIdx.x * 128;
  const unsigned short* vth = vt16 + (size_t)h * HD * DIM;
  f32x4 acc[2][4];
  for (int i = 0; i < 2; ++i) for (int j = 0; j < 4; ++j)
    for (int z = 0; z < 4; ++z) acc[i][j][z] = 0.f;

  for (int kt = 0; kt < DIM/32; ++kt){
    int k0 = kt * 32;
    __syncthreads();
    for (int rep = 0; rep < 2; ++rep){
      int id = t + rep * 256;              // 0..511
      int row = id >> 2, ko = (id & 3) * 8;
      GLOAD_LDS16(&xh[((size_t)(b*SEQ + m0 + row))*DIM + k0 + ko],
                  &lA[(rep*256 + w*64) * 8]);
    }
    { int row = t >> 2, ko = (t & 3) * 8;  // 64x32
      GLOAD_LDS16(&vth[(size_t)row*DIM + k0 + ko], &lB[(w*64) * 8]); }
    __syncthreads();
    half8 a[2];
    for (int i = 0; i < 2; ++i)
      a[i] = *(const half8*)&lA[(w*32 + i*16 + lane16)*32 + quad*8];
    for (int j = 0; j < 4; ++j){
      half8 bb = *(const half8*)&lB[(j*16 + lane16)*32 + quad*8];
      for (int i = 0; i < 2; ++i)
        acc[i][j] = __builtin_amdgcn_mfma_f32_16x16x32_f16(a[i], bb, acc[i][j], 0, 0, 0);
    }
  }
  // epilogue: transpose through LDS, contiguous row stores
  __syncthreads();
  for (int i = 0; i < 2; ++i) for (int j = 0; j < 4; ++j) for (int r = 0; r < 4; ++r){
    int col = j*16 + lane16;
    int n  = w*32 + i*16 + quad*4 + r;
    lOut[col*128 + n] = f2hu(acc[i][j][r]);
  }
  __syncthreads();
  for (int rep = 0; rep < 4; ++rep){
    int id = t + rep*256;                  // 0..1023 int4s
    int e = id >> 4, no = (id & 15) * 8;
    *(int4*)&xvT[((size_t)(b*NH + h)*HD + e)*SEQ + m0 + no] = *(const int4*)&lOut[e*128 + no];
  }
}

// ---------------- q projection (split-fp16 3-pass, XOR-swizzled LDS) ----------------
// q[bn][e] = sum_d x[bn][d] * Q_h[d][e]; grid (128 Mtiles, 6 Ntiles).
// tile 128x128, BK=64, 64 KB LDS -> 2 blocks/CU. LDS rows = 64 shorts (128 B);
// chunk c (16 B) of row r stored at slot c^(r&7) -> fragment reads bank-balanced.
__global__ __launch_bounds__(256, 2) void k_gemm_q(
    const unsigned short* __restrict__ xh, const unsigned short* __restrict__ xl,
    const unsigned short* __restrict__ bth, const unsigned short* __restrict__ btl,
    unsigned short* __restrict__ qh, unsigned short* __restrict__ ql){
  __shared__ __align__(16) unsigned short lA[2][128*64];   // [hl] 32 KB
  __shared__ __align__(16) unsigned short lB[2][128*64];   // [hl] 32 KB
  int t = threadIdx.x, w = t >> 6, l = t & 63;
  int lane16 = l & 15, quad = l >> 4;
  int m0 = blockIdx.x * 128, n0 = blockIdx.y * 128;
  int wr = (w >> 1) * 64, wc = (w & 1) * 64;
  f32x4 acc[4][4];
  for (int i = 0; i < 4; ++i) for (int j = 0; j < 4; ++j)
    for (int z = 0; z < 4; ++z) acc[i][j][z] = 0.f;

  for (int kt = 0; kt < DIM/64; ++kt){
    int k0 = kt * 64;
    __syncthreads();                       // previous compute's LDS reads done
    for (int rep = 0; rep < 4; ++rep){
      int id = t + rep * 256;              // 0..1023 (row, chunk)
      int row = id >> 3;
      int gc  = (id & 7) ^ (row & 7);      // fetch swizzled chunk into linear slot
      int lb  = (rep*256 + w*64) * 8;
      size_t gA = (size_t)(m0+row)*DIM + k0 + gc*8;
      size_t gB = (size_t)(n0+row)*DIM + k0 + gc*8;
      GLOAD_LDS16(&xh [gA], &lA[0][lb]);
      GLOAD_LDS16(&xl [gA], &lA[1][lb]);
      GLOAD_LDS16(&bth[gB], &lB[0][lb]);
      GLOAD_LDS16(&btl[gB], &lB[1][lb]);
    }
    __syncthreads();                       // drain staging
    for (int ks = 0; ks < 2; ++ks){
      int sw = ((ks*4 + quad) ^ (lane16 & 7)) * 8;   // swizzled chunk offset
      half8 aH[4], aL[4];
      for (int i = 0; i < 4; ++i){
        int r = wr + i*16 + lane16;
        aH[i] = *(const half8*)&lA[0][r*64 + sw];
        aL[i] = *(const half8*)&lA[1][r*64 + sw];
      }
      for (int j = 0; j < 4; ++j){
        int c = wc + j*16 + lane16;
        half8 bH = *(const half8*)&lB[0][c*64 + sw];
        half8 bL = *(const half8*)&lB[1][c*64 + sw];
        for (int i = 0; i < 4; ++i){
          acc[i][j] = __builtin_amdgcn_mfma_f32_16x16x32_f16(aL[i], bH, acc[i][j], 0, 0, 0);
          acc[i][j] = __builtin_amdgcn_mfma_f32_16x16x32_f16(aH[i], bL, acc[i][j], 0, 0, 0);
          acc[i][j] = __builtin_amdgcn_mfma_f32_16x16x32_f16(aH[i], bH, acc[i][j], 0, 0, 0);
        }
      }
    }
  }
  for (int i = 0; i < 4; ++i) for (int j = 0; j < 4; ++j) for (int r = 0; r < 4; ++r){
    int row = m0 + wr + i*16 + quad*4 + r;
    int col = n0 + wc + j*16 + lane16;
    float v = acc[i][j][r];
    _Float16 hh = (_Float16)v;
    size_t o = (size_t)row*DIM + col;
    qh[o] = h2u(hh);
    ql[o] = f2hu(v - (float)hh);
  }
}

// ---------------- fused attention per head ----------------
// grid (32 b, 8 nt) b-major (XCD L2 sharing of keys). block 512 (8 waves, 2/SIMD).
// BM=64 q-rows, full 512 keys; split-fp16 3-pass scores; BK=32 dbuf staging.
// Phase 1: wave w owns keys [64w, 64w+64). Phase 3: wave w owns K-slice [64w, 64w+64).
// LDS pool (shorts):
//   phase 1: keys[bb][hl]: bb*32768 + hl*16384 (128 KB); q[bb][hl]: 65536+bb*4096+hl*2048 (16 KB)
//   phase 2/3: lP rows 64 stride 520 @0; lXv rows 64 stride 520 @34816;
//              red float[32768] alias @0 after PV barrier (128 KB)
#define SEQP 520
__global__ __launch_bounds__(512) void k_attn(
    const unsigned short* __restrict__ qh, const unsigned short* __restrict__ ql,
    const unsigned short* __restrict__ xh, const unsigned short* __restrict__ xl,
    const unsigned short* __restrict__ xvT,
    float* __restrict__ out, int h){
  __shared__ __align__(16) unsigned short lsh[73728];   // 144 KB
  __shared__ float lStat[8*64 + 64 + 64];               // 2.5 KB

  int t = threadIdx.x, w = t >> 6, l = t & 63;
  int lane16 = l & 15, quad = l >> 4;
  int b = blockIdx.x, nt = blockIdx.y;
  int n0 = nt * 64;
  size_t rowbase = (size_t)b * SEQ;

  f32x4 accS[4][4];   // 4 q-row strips x 4 key strips (64 keys/wave)
  for (int i = 0; i < 4; ++i) for (int j = 0; j < 4; ++j)
    for (int z = 0; z < 4; ++z) accS[i][j][z] = 0.f;

  auto stage = [&](int kt){
    int k0 = kt * 32, bb = kt & 1;
    int qb = 65536 + bb*4096;
    // q 64x32 hi (waves 0-3) / lo (waves 4-7): 256 chunks each
    if (w < 4){
      int id = t;               // 0..255
      int row = id >> 2, ko = (id & 3) * 8;
      GLOAD_LDS16(&qh[(rowbase + n0 + row)*DIM + k0 + ko], &lsh[qb + w*512]);
    } else {
      int id = t - 256;
      int row = id >> 2, ko = (id & 3) * 8;
      GLOAD_LDS16(&ql[(rowbase + n0 + row)*DIM + k0 + ko], &lsh[qb + 2048 + (w-4)*512]);
    }
    int kb = bb*32768;
    for (int rep = 0; rep < 4; ++rep){      // keys hi 512x32 = 2048 chunks
      int id = t + rep * 512;
      int row = id >> 2, ko = (id & 3) * 8;
      GLOAD_LDS16(&xh[(rowbase + row)*DIM + k0 + ko], &lsh[kb + (rep*512 + w*64)*8]);
    }
    for (int rep = 0; rep < 4; ++rep){      // keys lo
      int id = t + rep * 512;
      int row = id >> 2, ko = (id & 3) * 8;
      GLOAD_LDS16(&xl[(rowbase + row)*DIM + k0 + ko], &lsh[kb + 16384 + (rep*512 + w*64)*8]);
    }
  };

  // ---- Phase 1: scores, double-buffered, 3-pass split ----
  stage(0);
  for (int kt = 0; kt < DIM/32; ++kt){
    __syncthreads();                 // drains staging of buffer kt&1
    if (kt + 1 < DIM/32) stage(kt + 1);   // prefetch in flight during compute
    int bb = kt & 1;
    int qb = 65536 + bb*4096, kb = bb*32768;
    half8 aH[4], aL[4];
    for (int i = 0; i < 4; ++i){
      int r = i*16 + lane16;
      aH[i] = *(const half8*)&lsh[qb + r*32 + quad*8];
      aL[i] = *(const half8*)&lsh[qb + 2048 + r*32 + quad*8];
    }
    for (int j = 0; j < 4; ++j){
      int c = w*64 + j*16 + lane16;
      half8 bH = *(const half8*)&lsh[kb + c*32 + quad*8];
      half8 bL = *(const half8*)&lsh[kb + 16384 + c*32 + quad*8];
      for (int i = 0; i < 4; ++i){
        accS[i][j] = __builtin_amdgcn_mfma_f32_16x16x32_f16(aL[i], bH, accS[i][j], 0, 0, 0);
        accS[i][j] = __builtin_amdgcn_mfma_f32_16x16x32_f16(aH[i], bL, accS[i][j], 0, 0, 0);
        accS[i][j] = __builtin_amdgcn_mfma_f32_16x16x32_f16(aH[i], bH, accS[i][j], 0, 0, 0);
      }
    }
  }
  __syncthreads();   // keys/q dead; repurpose pool

  // stage xvT[b,h] rows (512 fp16 = 1024 B = one wave-instr per row; pads between rows OK)
  const int XVB = 34816;
  for (int it = 0; it < 8; ++it){
    int e = it*8 + w;
    GLOAD_LDS16(&xvT[((size_t)(b*NH + h)*HD + e)*SEQ + l*8], &lsh[XVB + e*SEQP]);
  }

  // ---- Phase 2: softmax ----
  float rmx[4][4];
  for (int i = 0; i < 4; ++i) for (int r = 0; r < 4; ++r){
    float m = accS[i][0][r];
    for (int j = 1; j < 4; ++j) m = fmaxf(m, accS[i][j][r]);
    for (int d = 1; d < 16; d <<= 1) m = fmaxf(m, __shfl_xor(m, d, 64));
    rmx[i][r] = m;
  }
  if (lane16 == 0)
    for (int i = 0; i < 4; ++i) for (int r = 0; r < 4; ++r)
      lStat[w*64 + i*16 + quad*4 + r] = rmx[i][r];
  __syncthreads();
  if (t < 64){
    float m = lStat[t];
    for (int ww = 1; ww < 8; ++ww) m = fmaxf(m, lStat[ww*64 + t]);
    lStat[512 + t] = m;
  }
  __syncthreads();
  float rsum[4][4];
  for (int i = 0; i < 4; ++i) for (int r = 0; r < 4; ++r){
    float g = lStat[512 + i*16 + quad*4 + r];
    float s = 0.f;
    for (int j = 0; j < 4; ++j){
      float p = __expf(accS[i][j][r] - g);
      s += p;
      lsh[(i*16 + quad*4 + r)*SEQP + (w*64 + j*16 + lane16)] = f2hu(p);
    }
    for (int d = 1; d < 16; d <<= 1) s += __shfl_xor(s, d, 64);
    rsum[i][r] = s;
  }
  if (lane16 == 0)
    for (int i = 0; i < 4; ++i) for (int r = 0; r < 4; ++r)
      lStat[w*64 + i*16 + quad*4 + r] = rsum[i][r];
  __syncthreads();
  if (t < 64){
    float s = lStat[t];
    for (int ww = 1; ww < 8; ++ww) s += lStat[ww*64 + t];
    lStat[576 + t] = s;
  }
  __syncthreads();   // P + xv + sums visible

  // ---- Phase 3: PV (wave w owns K-slice [64w, 64w+64)) ----
  f32x4 accO[4][4];
  for (int i = 0; i < 4; ++i) for (int j = 0; j < 4; ++j)
    for (int z = 0; z < 4; ++z) accO[i][j][z] = 0.f;
  for (int ks = 0; ks < 2; ++ks){
    int kb = w*64 + ks*32;
    half8 aP[4];
    for (int i = 0; i < 4; ++i)
      aP[i] = *(const half8*)&lsh[(i*16 + lane16)*SEQP + kb + quad*8];
    for (int j = 0; j < 4; ++j){
      half8 bV = *(const half8*)&lsh[XVB + (j*16 + lane16)*SEQP + kb + quad*8];
      for (int i = 0; i < 4; ++i)
        accO[i][j] = __builtin_amdgcn_mfma_f32_16x16x32_f16(aP[i], bV, accO[i][j], 0, 0, 0);
    }
  }
  __syncthreads();   // all reads of lP/lXv done before overwrite
  float* red = (float*)lsh;
  for (int i = 0; i < 4; ++i) for (int j = 0; j < 4; ++j) for (int r = 0; r < 4; ++r)
    red[w*4096 + (i*16 + quad*4 + r)*64 + (j*16 + lane16)] = accO[i][j][r];
  __syncthreads();
  for (int z = t; z < 4096; z += 512){
    int row = z >> 6, col = z & 63;
    float v = 0.f;
    for (int ww = 0; ww < 8; ++ww) v += red[ww*4096 + z];
    v /= lStat[576 + row];
    out[(rowbase + n0 + row)*DIM + h*HD + col] = v;
  }
}

// ---------------- launcher ----------------
extern "C" void kernel_launch(void* const* d_in, const int* in_sizes, int n_in,
                              void* d_out, int out_size, void* d_ws, size_t ws_size,
                              hipStream_t stream){
  const float* x = (const float*)d_in[0];
  const float* Q = (const float*)d_in[1];
  const float* V = (const float*)d_in[2];
  float* out = (float*)d_out;

  char* ws = (char*)d_ws;
  size_t off = 0;
  auto alloc = [&](size_t bytes) -> void* {
    void* p = ws + off;
    off += (bytes + 255) & ~(size_t)255;
    return p;
  };
  unsigned short* xh  = (unsigned short*)alloc((size_t)ROWS*DIM*2);       // 25.2 MB
  unsigned short* xl  = (unsigned short*)alloc((size_t)ROWS*DIM*2);       // 25.2 MB
  unsigned short* qth = (unsigned short*)alloc((size_t)NH*DIM*DIM*2);     // 14.2 MB
  unsigned short* qtl = (unsigned short*)alloc((size_t)NH*DIM*DIM*2);     // 14.2 MB
  unsigned short* vt  = (unsigned short*)alloc((size_t)NH*HD*DIM*2);      //  1.2 MB
  unsigned short* xvT = (unsigned short*)alloc((size_t)B_SZ*NH*HD*SEQ*2); // 25.2 MB
  unsigned short* qh  = (unsigned short*)alloc((size_t)ROWS*DIM*2);       // 25.2 MB (per-head reuse)
  unsigned short* ql  = (unsigned short*)alloc((size_t)ROWS*DIM*2);       // 25.2 MB
  // total ~155.6 MB

  int n4 = ROWS*DIM/4;
  k_split<<<n4/256, 256, 0, stream>>>(x, xh, xl, n4);
  k_transQ<<<dim3(DIM/32, DIM/32, NH), 256, 0, stream>>>(Q, qth, qtl);
  k_transV<<<dim3(DIM/32, HD/32, NH), 256, 0, stream>>>(V, vt);
  k_gemm_xv<<<dim3(4, B_SZ, NH), 256, 0, stream>>>(xh, vt, xvT);

  for (int h = 0; h < NH; ++h){
    k_gemm_q<<<dim3(ROWS/128, DIM/128), 256, 0, stream>>>(
        xh, xl, qth + (size_t)h*DIM*DIM, qtl + (size_t)h*DIM*DIM, qh, ql);
    k_attn<<<dim3(B_SZ, SEQ/64), 512, 0, stream>>>(qh, ql, xh, xl, xvT, out, h);
  }
}